// Round 1
// baseline (4487.770 us; speedup 1.0000x reference)
//
#include <hip/hip_runtime.h>
#include <hip/hip_bf16.h>

#define N_NODES 50000
#define N_EDGES 500000
#define E2_EDGES 550000   // with self loops appended
#define F_IN 32
#define HEADS 4
#define CH 64
#define HC 256            // HEADS*CH
#define NB 1000
#define NHID 256
#define NOUT 256

static inline int cdiv(long long a, long long b) { return (int)((a + b - 1) / b); }

// ---------- order-preserving float<->uint key for atomicMax ----------
__device__ inline unsigned fkey(float f) {
    unsigned u = __float_as_uint(f);
    return (u & 0x80000000u) ? ~u : (u ^ 0x80000000u);
}
__device__ inline float fdec(unsigned k) {
    unsigned u = (k & 0x80000000u) ? (k ^ 0x80000000u) : ~k;
    return __uint_as_float(u);
}

// ---------- generic small GEMM: C[N,M] = A[N,K] @ W[K,M] (+bias,relu) ----------
// A row-major, W row-major. BLOCK threads, TM rows per block.
template<int K, int M, int TM, int BLOCK, bool RELU>
__global__ __launch_bounds__(BLOCK) void lin_kernel(
    const float* __restrict__ A, const float* __restrict__ W,
    const float* __restrict__ bias, float* __restrict__ C, int n_rows) {
    __shared__ float As[TM][K];
    const int n0 = blockIdx.x * TM;
    const int tid = threadIdx.x;
    for (int idx = tid; idx < TM * K; idx += BLOCK) {
        int r = idx / K, c = idx % K;
        int n = n0 + r;
        As[r][c] = (n < n_rows) ? A[(size_t)n * K + c] : 0.f;
    }
    __syncthreads();
    constexpr int G = BLOCK / M;     // row groups
    constexpr int RPT = TM / G;      // rows per group
    const int j = tid % M;
    const int g = tid / M;
    float acc[RPT];
#pragma unroll
    for (int i = 0; i < RPT; i++) acc[i] = 0.f;
    for (int k = 0; k < K; k++) {
        float wk = W[(size_t)k * M + j];
#pragma unroll
        for (int i = 0; i < RPT; i++) acc[i] += As[g * RPT + i][k] * wk;
    }
    float bv = bias ? bias[j] : 0.f;
#pragma unroll
    for (int i = 0; i < RPT; i++) {
        int n = n0 + g * RPT + i;
        if (n < n_rows) {
            float v = acc[i] + bv;
            if (RELU) v = fmaxf(v, 0.f);
            C[(size_t)n * M + j] = v;
        }
    }
}

// ---------- per-(node,head) attention logits ----------
template<int H_, int C_>
__global__ void attn_logits_kernel(const float* __restrict__ h,
                                   const float* __restrict__ a_src,
                                   const float* __restrict__ a_dst,
                                   float* __restrict__ als, float* __restrict__ ald,
                                   int n) {
    int t = blockIdx.x * blockDim.x + threadIdx.x;
    if (t >= n * H_) return;
    int node = t / H_, hh = t % H_;
    const float* hp = h + (size_t)node * (H_ * C_) + hh * C_;
    const float* as = a_src + hh * C_;
    const float* ad = a_dst + hh * C_;
    float ss = 0.f, sd = 0.f;
#pragma unroll 8
    for (int c = 0; c < C_; c++) {
        float v = hp[c];
        ss += v * as[c];
        sd += v * ad[c];
    }
    als[t] = ss;
    ald[t] = sd;
}

// ---------- per-edge segment max ----------
template<int H_>
__global__ void edge_max_kernel(const int* __restrict__ ei,
                                unsigned* __restrict__ mkey,
                                const float* __restrict__ als,
                                const float* __restrict__ ald) {
    int t = blockIdx.x * blockDim.x + threadIdx.x;
    if (t >= E2_EDGES * H_) return;
    int e = t / H_, hh = t % H_;
    int s, d;
    if (e < N_EDGES) { s = ei[e]; d = ei[N_EDGES + e]; }
    else             { s = d = e - N_EDGES; }
    float x = als[s * H_ + hh] + ald[d * H_ + hh];
    x = (x > 0.f) ? x : 0.2f * x;               // leaky_relu 0.2
    atomicMax(mkey + d * H_ + hh, fkey(x));
}

// ---------- per-edge exp + scatter-add aggregation (unnormalized) ----------
// one wave (64 lanes) per edge; CPT = H_*C_/64 channels per lane
template<int H_, int C_, int EPB>
__global__ __launch_bounds__(EPB * 64) void edge_agg_kernel(
    const int* __restrict__ ei, const float* __restrict__ h,
    const unsigned* __restrict__ mkey, const float* __restrict__ als,
    const float* __restrict__ ald, float* __restrict__ z,
    float* __restrict__ out) {
    constexpr int HCL = H_ * C_;
    constexpr int CPT = HCL / 64;
    const int lane = threadIdx.x & 63;
    const int e = blockIdx.x * EPB + (threadIdx.x >> 6);
    if (e >= E2_EDGES) return;
    int s, d;
    if (e < N_EDGES) { s = ei[e]; d = ei[N_EDGES + e]; }
    else             { s = d = e - N_EDGES; }
    const int c0 = lane * CPT;
    const int hh = c0 / C_;
    float x = als[s * H_ + hh] + ald[d * H_ + hh];
    x = (x > 0.f) ? x : 0.2f * x;
    float m = fdec(mkey[d * H_ + hh]);
    float p = __expf(x - m);
    if ((c0 % C_) == 0) atomicAdd(z + d * H_ + hh, p);
    const float* hs = h + (size_t)s * HCL + c0;
    float* od = out + (size_t)d * HCL + c0;
    if (CPT == 4) {
        float4 hv = *(const float4*)hs;
        atomicAdd(od + 0, p * hv.x);
        atomicAdd(od + 1, p * hv.y);
        atomicAdd(od + 2, p * hv.z);
        atomicAdd(od + 3, p * hv.w);
    } else {
        atomicAdd(od, p * hs[0]);
    }
}

// ---------- normalize by z, add bias, optional relu ----------
template<int H_, int C_, bool RELU>
__global__ void finalize_kernel(float* __restrict__ out, const float* __restrict__ z,
                                const float* __restrict__ bias, int n) {
    constexpr int HCL = H_ * C_;
    int t = blockIdx.x * blockDim.x + threadIdx.x;
    if (t >= n * HCL) return;
    int node = t / HCL, c = t % HCL, hh = c / C_;
    float v = out[t] / (z[node * H_ + hh] + 1e-16f) + bias[c];
    if (RELU) v = fmaxf(v, 0.f);
    out[t] = v;
}

// ---------- mean pooling over batch ----------
__global__ void pool_sum_kernel(const float* __restrict__ h3, const int* __restrict__ batch,
                                float* __restrict__ xg, float* __restrict__ cnt) {
    int t = blockIdx.x * blockDim.x + threadIdx.x;
    if (t >= N_NODES * CH) return;
    int n = t >> 6, c = t & 63;
    int b = batch[n];
    atomicAdd(xg + b * CH + c, h3[t]);
    if (c == 0) atomicAdd(cnt + b, 1.f);
}
__global__ void pool_div_kernel(float* __restrict__ xg, const float* __restrict__ cnt) {
    int t = blockIdx.x * blockDim.x + threadIdx.x;
    if (t >= NB * CH) return;
    xg[t] /= fmaxf(cnt[t >> 6], 1.f);
}

// ---------- MLP layer 2 + LayerNorm, one block per graph ----------
__global__ __launch_bounds__(256) void mlp2_ln_kernel(
    const float* __restrict__ y1, const float* __restrict__ Wm2,
    const float* __restrict__ bm2, const float* __restrict__ g2,
    const float* __restrict__ be2, float* __restrict__ out) {
    const int b = blockIdx.x;
    const int j = threadIdx.x;
    __shared__ float yr[NHID];
    yr[j] = y1[(size_t)b * NHID + j];
    __syncthreads();
    float acc = bm2[j];
#pragma unroll 8
    for (int k = 0; k < NHID; k++) acc += yr[k] * Wm2[(size_t)k * NOUT + j];
    // block reduce sum and sumsq over 256 threads (4 waves)
    float s = acc, s2 = acc * acc;
    for (int o = 32; o > 0; o >>= 1) {
        s += __shfl_down(s, o);
        s2 += __shfl_down(s2, o);
    }
    __shared__ float red[8];
    __shared__ float mv[2];
    int wave = j >> 6, lane = j & 63;
    if (lane == 0) { red[wave] = s; red[4 + wave] = s2; }
    __syncthreads();
    if (j == 0) {
        float ts = red[0] + red[1] + red[2] + red[3];
        float ts2 = red[4] + red[5] + red[6] + red[7];
        float mu = ts / (float)NOUT;
        float var = ts2 / (float)NOUT - mu * mu;
        mv[0] = mu;
        mv[1] = rsqrtf(var + 1e-5f);
    }
    __syncthreads();
    out[(size_t)b * NOUT + j] = (acc - mv[0]) * mv[1] * g2[j] + be2[j];
}

extern "C" void kernel_launch(void* const* d_in, const int* in_sizes, int n_in,
                              void* d_out, int out_size, void* d_ws, size_t ws_size,
                              hipStream_t stream) {
    const float* x      = (const float*)d_in[0];
    const int*   ei     = (const int*)d_in[1];
    const int*   batch  = (const int*)d_in[2];
    const float* W1     = (const float*)d_in[3];
    const float* as1    = (const float*)d_in[4];
    const float* ad1    = (const float*)d_in[5];
    const float* b1     = (const float*)d_in[6];
    const float* W2     = (const float*)d_in[7];
    const float* as2    = (const float*)d_in[8];
    const float* ad2    = (const float*)d_in[9];
    const float* b2     = (const float*)d_in[10];
    const float* W3     = (const float*)d_in[11];
    const float* as3    = (const float*)d_in[12];
    const float* ad3    = (const float*)d_in[13];
    const float* b3     = (const float*)d_in[14];
    const float* Wm1    = (const float*)d_in[15];
    const float* bm1    = (const float*)d_in[16];
    const float* Wm2    = (const float*)d_in[17];
    const float* bm2    = (const float*)d_in[18];
    const float* g2     = (const float*)d_in[19];
    const float* be2    = (const float*)d_in[20];
    float* out = (float*)d_out;

    // workspace layout
    float*    bufH = (float*)d_ws;                       // N*HC
    float*    bufO = bufH + (size_t)N_NODES * HC;        // N*HC
    unsigned* mkey = (unsigned*)(bufO + (size_t)N_NODES * HC);  // N*HEADS
    float*    zbuf = (float*)(mkey + (size_t)N_NODES * HEADS);  // N*HEADS
    float*    als  = zbuf + (size_t)N_NODES * HEADS;     // N*HEADS
    float*    ald  = als + (size_t)N_NODES * HEADS;      // N*HEADS
    float*    xg   = ald + (size_t)N_NODES * HEADS;      // NB*CH
    float*    cnt  = xg + (size_t)NB * CH;               // NB
    float*    y1   = cnt + NB;                           // NB*NHID

    const int BLK = 256;

    // ===================== Layer 1 (F_IN -> H*C) =====================
    hipMemsetAsync(bufO, 0, (size_t)N_NODES * HC * sizeof(float), stream);
    hipMemsetAsync(mkey, 0, (size_t)N_NODES * HEADS * sizeof(unsigned), stream);
    hipMemsetAsync(zbuf, 0, (size_t)N_NODES * HEADS * sizeof(float), stream);
    lin_kernel<F_IN, HC, 16, 256, false><<<cdiv(N_NODES, 16), 256, 0, stream>>>(
        x, W1, nullptr, bufH, N_NODES);
    attn_logits_kernel<HEADS, CH><<<cdiv((long long)N_NODES * HEADS, BLK), BLK, 0, stream>>>(
        bufH, as1, ad1, als, ald, N_NODES);
    edge_max_kernel<HEADS><<<cdiv((long long)E2_EDGES * HEADS, BLK), BLK, 0, stream>>>(
        ei, mkey, als, ald);
    edge_agg_kernel<HEADS, CH, 4><<<cdiv(E2_EDGES, 4), 256, 0, stream>>>(
        ei, bufH, mkey, als, ald, zbuf, bufO);
    finalize_kernel<HEADS, CH, true><<<cdiv((long long)N_NODES * HC, BLK), BLK, 0, stream>>>(
        bufO, zbuf, b1, N_NODES);

    // ===================== Layer 2 (H*C -> H*C) =====================
    lin_kernel<HC, HC, 16, 256, false><<<cdiv(N_NODES, 16), 256, 0, stream>>>(
        bufO, W2, nullptr, bufH, N_NODES);
    attn_logits_kernel<HEADS, CH><<<cdiv((long long)N_NODES * HEADS, BLK), BLK, 0, stream>>>(
        bufH, as2, ad2, als, ald, N_NODES);
    hipMemsetAsync(bufO, 0, (size_t)N_NODES * HC * sizeof(float), stream);
    hipMemsetAsync(mkey, 0, (size_t)N_NODES * HEADS * sizeof(unsigned), stream);
    hipMemsetAsync(zbuf, 0, (size_t)N_NODES * HEADS * sizeof(float), stream);
    edge_max_kernel<HEADS><<<cdiv((long long)E2_EDGES * HEADS, BLK), BLK, 0, stream>>>(
        ei, mkey, als, ald);
    edge_agg_kernel<HEADS, CH, 4><<<cdiv(E2_EDGES, 4), 256, 0, stream>>>(
        ei, bufH, mkey, als, ald, zbuf, bufO);
    finalize_kernel<HEADS, CH, true><<<cdiv((long long)N_NODES * HC, BLK), BLK, 0, stream>>>(
        bufO, zbuf, b2, N_NODES);

    // ===================== Layer 3 (H*C -> C, heads=1) =====================
    lin_kernel<HC, CH, 16, 256, false><<<cdiv(N_NODES, 16), 256, 0, stream>>>(
        bufO, W3, nullptr, bufH, N_NODES);
    attn_logits_kernel<1, CH><<<cdiv(N_NODES, BLK), BLK, 0, stream>>>(
        bufH, as3, ad3, als, ald, N_NODES);
    hipMemsetAsync(bufO, 0, (size_t)N_NODES * CH * sizeof(float), stream);
    hipMemsetAsync(mkey, 0, (size_t)N_NODES * sizeof(unsigned), stream);
    hipMemsetAsync(zbuf, 0, (size_t)N_NODES * sizeof(float), stream);
    edge_max_kernel<1><<<cdiv(E2_EDGES, BLK), BLK, 0, stream>>>(
        ei, mkey, als, ald);
    edge_agg_kernel<1, CH, 4><<<cdiv(E2_EDGES, 4), 256, 0, stream>>>(
        ei, bufH, mkey, als, ald, zbuf, bufO);
    finalize_kernel<1, CH, false><<<cdiv((long long)N_NODES * CH, BLK), BLK, 0, stream>>>(
        bufO, zbuf, b3, N_NODES);

    // ===================== Mean pooling =====================
    hipMemsetAsync(xg, 0, ((size_t)NB * CH + NB) * sizeof(float), stream);
    pool_sum_kernel<<<cdiv((long long)N_NODES * CH, BLK), BLK, 0, stream>>>(
        bufO, batch, xg, cnt);
    pool_div_kernel<<<cdiv(NB * CH, BLK), BLK, 0, stream>>>(xg, cnt);

    // ===================== MLP head + LayerNorm =====================
    lin_kernel<CH, NHID, 16, 256, true><<<cdiv(NB, 16), 256, 0, stream>>>(
        xg, Wm1, bm1, y1, NB);
    mlp2_ln_kernel<<<NB, 256, 0, stream>>>(y1, Wm2, bm2, g2, be2, out);
}

// Round 2
// 1201.423 us; speedup vs baseline: 3.7354x; 3.7354x over previous
//
#include <hip/hip_runtime.h>
#include <hip/hip_bf16.h>

#define N_NODES 50000
#define N_EDGES 500000
#define E2_EDGES 550000   // with self loops appended
#define F_IN 32
#define HEADS 4
#define CH 64
#define HC 256            // HEADS*CH
#define NB 1000
#define NHID 256
#define NOUT 256

static inline int cdiv(long long a, long long b) { return (int)((a + b - 1) / b); }

// ---------- generic small GEMM: C[N,M] = A[N,K] @ W[K,M] (+bias,relu) ----------
template<int K, int M, int TM, int BLOCK, bool RELU>
__global__ __launch_bounds__(BLOCK) void lin_kernel(
    const float* __restrict__ A, const float* __restrict__ W,
    const float* __restrict__ bias, float* __restrict__ C, int n_rows) {
    __shared__ float As[TM][K];
    const int n0 = blockIdx.x * TM;
    const int tid = threadIdx.x;
    for (int idx = tid; idx < TM * K; idx += BLOCK) {
        int r = idx / K, c = idx % K;
        int n = n0 + r;
        As[r][c] = (n < n_rows) ? A[(size_t)n * K + c] : 0.f;
    }
    __syncthreads();
    constexpr int G = BLOCK / M;     // row groups
    constexpr int RPT = TM / G;      // rows per group
    const int j = tid % M;
    const int g = tid / M;
    float acc[RPT];
#pragma unroll
    for (int i = 0; i < RPT; i++) acc[i] = 0.f;
    for (int k = 0; k < K; k++) {
        float wk = W[(size_t)k * M + j];
#pragma unroll
        for (int i = 0; i < RPT; i++) acc[i] += As[g * RPT + i][k] * wk;
    }
    float bv = bias ? bias[j] : 0.f;
#pragma unroll
    for (int i = 0; i < RPT; i++) {
        int n = n0 + g * RPT + i;
        if (n < n_rows) {
            float v = acc[i] + bv;
            if (RELU) v = fmaxf(v, 0.f);
            C[(size_t)n * M + j] = v;
        }
    }
}

// ---------- per-(node,head) attention logits ----------
template<int H_, int C_>
__global__ void attn_logits_kernel(const float* __restrict__ h,
                                   const float* __restrict__ a_src,
                                   const float* __restrict__ a_dst,
                                   float* __restrict__ als, float* __restrict__ ald,
                                   int n) {
    int t = blockIdx.x * blockDim.x + threadIdx.x;
    if (t >= n * H_) return;
    int node = t / H_, hh = t % H_;
    const float* hp = h + (size_t)node * (H_ * C_) + hh * C_;
    const float* as = a_src + hh * C_;
    const float* ad = a_dst + hh * C_;
    float ss = 0.f, sd = 0.f;
#pragma unroll 8
    for (int c = 0; c < C_; c++) {
        float v = hp[c];
        ss += v * as[c];
        sd += v * ad[c];
    }
    als[t] = ss;
    ald[t] = sd;
}

// ======================= CSR build =======================
__global__ void hist_kernel(const int* __restrict__ ei, int* __restrict__ deg) {
    int e = blockIdx.x * blockDim.x + threadIdx.x;
    if (e >= E2_EDGES) return;
    int d = (e < N_EDGES) ? ei[N_EDGES + e] : (e - N_EDGES);
    atomicAdd(deg + d, 1);
}

// per-1024-chunk exclusive scan; writes partials into rowptr, chunk totals to bsum
__global__ __launch_bounds__(256) void scan_block_kernel(const int* __restrict__ deg,
                                                         int* __restrict__ rowptr,
                                                         int* __restrict__ bsum) {
    __shared__ int sdata[256];
    const int b = blockIdx.x, t = threadIdx.x;
    const int base = b * 1024 + t * 4;
    int v[4]; int s = 0;
#pragma unroll
    for (int i = 0; i < 4; i++) {
        int idx = base + i;
        v[i] = (idx < N_NODES) ? deg[idx] : 0;
        s += v[i];
    }
    sdata[t] = s;
    __syncthreads();
    for (int o = 1; o < 256; o <<= 1) {
        int x = (t >= o) ? sdata[t - o] : 0;
        __syncthreads();
        sdata[t] += x;
        __syncthreads();
    }
    if (t == 255) bsum[b] = sdata[255];
    int run = sdata[t] - s;   // exclusive prefix of this thread's chunk
#pragma unroll
    for (int i = 0; i < 4; i++) {
        int idx = base + i;
        if (idx < N_NODES) rowptr[idx] = run;
        run += v[i];
    }
}

__global__ void scan_bsum_kernel(int* __restrict__ bsum, int nb) {
    if (threadIdx.x == 0 && blockIdx.x == 0) {
        int run = 0;
        for (int i = 0; i < nb; i++) { int v = bsum[i]; bsum[i] = run; run += v; }
    }
}

__global__ void finalize_rowptr_kernel(int* __restrict__ rowptr, const int* __restrict__ bsum,
                                       int* __restrict__ cursor) {
    int i = blockIdx.x * blockDim.x + threadIdx.x;
    if (i >= N_NODES) return;
    int v = rowptr[i] + bsum[i >> 10];
    rowptr[i] = v;
    cursor[i] = v;
}

__global__ void scatter_kernel(const int* __restrict__ ei, int* __restrict__ cursor,
                               int* __restrict__ csr_src) {
    int e = blockIdx.x * blockDim.x + threadIdx.x;
    if (e >= E2_EDGES) return;
    int s, d;
    if (e < N_EDGES) { s = ei[e]; d = ei[N_EDGES + e]; }
    else             { s = d = e - N_EDGES; }
    int pos = atomicAdd(cursor + d, 1);
    csr_src[pos] = s;
}

// ======================= gather-based GAT aggregation =======================
// TPN = H_*C_ threads per node; thread `local` owns output channel `local`.
template<int H_, int C_, int NPB, bool RELU>
__global__ __launch_bounds__(NPB * H_ * C_) void gat_agg_csr_kernel(
    const int* __restrict__ csr_src, const int* __restrict__ rowptr,
    const int* __restrict__ deg, const float* __restrict__ h,
    const float* __restrict__ als, const float* __restrict__ ald,
    const float* __restrict__ bias, float* __restrict__ out, int n) {
    constexpr int TPN = H_ * C_;
    const int local = threadIdx.x % TPN;
    const int node = blockIdx.x * NPB + threadIdx.x / TPN;
    if (node >= n) return;
    const int hh = local / C_;
    const int start = rowptr[node];
    const int len = deg[node];
    const float ad = ald[node * H_ + hh];
    // pass 1: segment max over incoming edges (len >= 1 due to self-loop)
    float m = -1e30f;
    for (int k = 0; k < len; k++) {
        int s = csr_src[start + k];
        float x = als[s * H_ + hh] + ad;
        x = (x > 0.f) ? x : 0.2f * x;
        m = fmaxf(m, x);
    }
    // pass 2: exp-weighted gather accumulate
    float z = 0.f, acc = 0.f;
    for (int k = 0; k < len; k++) {
        int s = csr_src[start + k];
        float x = als[s * H_ + hh] + ad;
        x = (x > 0.f) ? x : 0.2f * x;
        float p = __expf(x - m);
        z += p;
        acc += p * h[(size_t)s * TPN + local];
    }
    float v = acc / (z + 1e-16f) + bias[local];
    if (RELU) v = fmaxf(v, 0.f);
    out[(size_t)node * TPN + local] = v;
}

// ---------- mean pooling over (sorted) batch via binary search ----------
__global__ __launch_bounds__(64) void pool_kernel(const float* __restrict__ h3,
                                                  const int* __restrict__ batch,
                                                  float* __restrict__ xg) {
    const int b = blockIdx.x;
    const int j = threadIdx.x;     // channel 0..63
    int lo = 0, hi = N_NODES;
    while (lo < hi) { int mid = (lo + hi) >> 1; if (batch[mid] < b) lo = mid + 1; else hi = mid; }
    const int start = lo;
    hi = N_NODES;
    while (lo < hi) { int mid = (lo + hi) >> 1; if (batch[mid] < b + 1) lo = mid + 1; else hi = mid; }
    const int end = lo;
    float s = 0.f;
    for (int n = start; n < end; n++) s += h3[(size_t)n * CH + j];
    xg[b * CH + j] = s / fmaxf((float)(end - start), 1.f);
}

// ---------- MLP layer 2 + LayerNorm, one block per graph ----------
__global__ __launch_bounds__(256) void mlp2_ln_kernel(
    const float* __restrict__ y1, const float* __restrict__ Wm2,
    const float* __restrict__ bm2, const float* __restrict__ g2,
    const float* __restrict__ be2, float* __restrict__ out) {
    const int b = blockIdx.x;
    const int j = threadIdx.x;
    __shared__ float yr[NHID];
    yr[j] = y1[(size_t)b * NHID + j];
    __syncthreads();
    float acc = bm2[j];
#pragma unroll 8
    for (int k = 0; k < NHID; k++) acc += yr[k] * Wm2[(size_t)k * NOUT + j];
    float s = acc, s2 = acc * acc;
    for (int o = 32; o > 0; o >>= 1) {
        s += __shfl_down(s, o);
        s2 += __shfl_down(s2, o);
    }
    __shared__ float red[8];
    __shared__ float mv[2];
    int wave = j >> 6, lane = j & 63;
    if (lane == 0) { red[wave] = s; red[4 + wave] = s2; }
    __syncthreads();
    if (j == 0) {
        float ts = red[0] + red[1] + red[2] + red[3];
        float ts2 = red[4] + red[5] + red[6] + red[7];
        float mu = ts / (float)NOUT;
        float var = ts2 / (float)NOUT - mu * mu;
        mv[0] = mu;
        mv[1] = rsqrtf(var + 1e-5f);
    }
    __syncthreads();
    out[(size_t)b * NOUT + j] = (acc - mv[0]) * mv[1] * g2[j] + be2[j];
}

extern "C" void kernel_launch(void* const* d_in, const int* in_sizes, int n_in,
                              void* d_out, int out_size, void* d_ws, size_t ws_size,
                              hipStream_t stream) {
    const float* x      = (const float*)d_in[0];
    const int*   ei     = (const int*)d_in[1];
    const int*   batch  = (const int*)d_in[2];
    const float* W1     = (const float*)d_in[3];
    const float* as1    = (const float*)d_in[4];
    const float* ad1    = (const float*)d_in[5];
    const float* b1     = (const float*)d_in[6];
    const float* W2     = (const float*)d_in[7];
    const float* as2    = (const float*)d_in[8];
    const float* ad2    = (const float*)d_in[9];
    const float* b2     = (const float*)d_in[10];
    const float* W3     = (const float*)d_in[11];
    const float* as3    = (const float*)d_in[12];
    const float* ad3    = (const float*)d_in[13];
    const float* b3     = (const float*)d_in[14];
    const float* Wm1    = (const float*)d_in[15];
    const float* bm1    = (const float*)d_in[16];
    const float* Wm2    = (const float*)d_in[17];
    const float* bm2    = (const float*)d_in[18];
    const float* g2     = (const float*)d_in[19];
    const float* be2    = (const float*)d_in[20];
    float* out = (float*)d_out;

    // workspace layout
    float* bufH = (float*)d_ws;                          // N*HC
    float* bufO = bufH + (size_t)N_NODES * HC;           // N*HC
    float* als  = bufO + (size_t)N_NODES * HC;           // N*HEADS
    float* ald  = als + (size_t)N_NODES * HEADS;         // N*HEADS
    float* xg   = ald + (size_t)N_NODES * HEADS;         // NB*CH
    float* y1   = xg + (size_t)NB * CH;                  // NB*NHID
    int* deg     = (int*)(y1 + (size_t)NB * NHID);       // N
    int* rowptr  = deg + N_NODES;                        // N
    int* cursor  = rowptr + N_NODES;                     // N
    int* bsum    = cursor + N_NODES;                     // cdiv(N,1024)
    int* csr_src = bsum + 64;                            // E2

    const int BLK = 256;
    const int NSCAN = cdiv(N_NODES, 1024);

    // ===================== CSR build (dst-sorted adjacency) =====================
    hipMemsetAsync(deg, 0, (size_t)N_NODES * sizeof(int), stream);
    hist_kernel<<<cdiv(E2_EDGES, BLK), BLK, 0, stream>>>(ei, deg);
    scan_block_kernel<<<NSCAN, 256, 0, stream>>>(deg, rowptr, bsum);
    scan_bsum_kernel<<<1, 64, 0, stream>>>(bsum, NSCAN);
    finalize_rowptr_kernel<<<cdiv(N_NODES, BLK), BLK, 0, stream>>>(rowptr, bsum, cursor);
    scatter_kernel<<<cdiv(E2_EDGES, BLK), BLK, 0, stream>>>(ei, cursor, csr_src);

    // ===================== Layer 1 (F_IN -> H*C) =====================
    lin_kernel<F_IN, HC, 16, 256, false><<<cdiv(N_NODES, 16), 256, 0, stream>>>(
        x, W1, nullptr, bufH, N_NODES);
    attn_logits_kernel<HEADS, CH><<<cdiv((long long)N_NODES * HEADS, BLK), BLK, 0, stream>>>(
        bufH, as1, ad1, als, ald, N_NODES);
    gat_agg_csr_kernel<HEADS, CH, 1, true><<<N_NODES, HC, 0, stream>>>(
        csr_src, rowptr, deg, bufH, als, ald, b1, bufO, N_NODES);

    // ===================== Layer 2 (H*C -> H*C) =====================
    lin_kernel<HC, HC, 16, 256, false><<<cdiv(N_NODES, 16), 256, 0, stream>>>(
        bufO, W2, nullptr, bufH, N_NODES);
    attn_logits_kernel<HEADS, CH><<<cdiv((long long)N_NODES * HEADS, BLK), BLK, 0, stream>>>(
        bufH, as2, ad2, als, ald, N_NODES);
    gat_agg_csr_kernel<HEADS, CH, 1, true><<<N_NODES, HC, 0, stream>>>(
        csr_src, rowptr, deg, bufH, als, ald, b2, bufO, N_NODES);

    // ===================== Layer 3 (H*C -> C, heads=1) =====================
    lin_kernel<HC, CH, 16, 256, false><<<cdiv(N_NODES, 16), 256, 0, stream>>>(
        bufO, W3, nullptr, bufH, N_NODES);
    attn_logits_kernel<1, CH><<<cdiv(N_NODES, BLK), BLK, 0, stream>>>(
        bufH, as3, ad3, als, ald, N_NODES);
    gat_agg_csr_kernel<1, CH, 4, false><<<cdiv(N_NODES, 4), 256, 0, stream>>>(
        csr_src, rowptr, deg, bufH, als, ald, b3, bufO, N_NODES);

    // ===================== Mean pooling (batch is sorted) =====================
    pool_kernel<<<NB, 64, 0, stream>>>(bufO, batch, xg);

    // ===================== MLP head + LayerNorm =====================
    lin_kernel<CH, NHID, 16, 256, true><<<cdiv(NB, 16), 256, 0, stream>>>(
        xg, Wm1, bm1, y1, NB);
    mlp2_ln_kernel<<<NB, 256, 0, stream>>>(y1, Wm2, bm2, g2, be2, out);
}

// Round 3
// 717.883 us; speedup vs baseline: 6.2514x; 1.6736x over previous
//
#include <hip/hip_runtime.h>
#include <hip/hip_bf16.h>

#define N_NODES 50000
#define N_EDGES 500000
#define E2_EDGES 550000   // with self loops appended
#define F_IN 32
#define HEADS 4
#define CH 64
#define HC 256            // HEADS*CH
#define NB 1000
#define NHID 256
#define NOUT 256

static inline int cdiv(long long a, long long b) { return (int)((a + b - 1) / b); }

// ---------- generic small GEMM: C[N,M] = A[N,K] @ W[K,M] (+bias,relu) ----------
template<int K, int M, int TM, int BLOCK, bool RELU>
__global__ __launch_bounds__(BLOCK) void lin_kernel(
    const float* __restrict__ A, const float* __restrict__ W,
    const float* __restrict__ bias, float* __restrict__ C, int n_rows) {
    __shared__ float As[TM][K];
    const int n0 = blockIdx.x * TM;
    const int tid = threadIdx.x;
    for (int idx = tid; idx < TM * K; idx += BLOCK) {
        int r = idx / K, c = idx % K;
        int n = n0 + r;
        As[r][c] = (n < n_rows) ? A[(size_t)n * K + c] : 0.f;
    }
    __syncthreads();
    constexpr int G = BLOCK / M;     // row groups
    constexpr int RPT = TM / G;      // rows per group
    const int j = tid % M;
    const int g = tid / M;
    float acc[RPT];
#pragma unroll
    for (int i = 0; i < RPT; i++) acc[i] = 0.f;
    for (int k = 0; k < K; k++) {
        float wk = W[(size_t)k * M + j];
#pragma unroll
        for (int i = 0; i < RPT; i++) acc[i] += As[g * RPT + i][k] * wk;
    }
    float bv = bias ? bias[j] : 0.f;
#pragma unroll
    for (int i = 0; i < RPT; i++) {
        int n = n0 + g * RPT + i;
        if (n < n_rows) {
            float v = acc[i] + bv;
            if (RELU) v = fmaxf(v, 0.f);
            C[(size_t)n * M + j] = v;
        }
    }
}

// ---------- per-(node,head) attention logits (float4 loads) ----------
template<int H_, int C_>
__global__ void attn_logits_kernel(const float* __restrict__ h,
                                   const float* __restrict__ a_src,
                                   const float* __restrict__ a_dst,
                                   float* __restrict__ als, float* __restrict__ ald,
                                   int n) {
    int t = blockIdx.x * blockDim.x + threadIdx.x;
    if (t >= n * H_) return;
    int node = t / H_, hh = t % H_;
    const float4* hp = (const float4*)(h + (size_t)node * (H_ * C_) + hh * C_);
    const float4* as = (const float4*)(a_src + hh * C_);
    const float4* ad = (const float4*)(a_dst + hh * C_);
    float ss = 0.f, sd = 0.f;
#pragma unroll
    for (int c = 0; c < C_ / 4; c++) {
        float4 v = hp[c], a = as[c], b = ad[c];
        ss += v.x * a.x + v.y * a.y + v.z * a.z + v.w * a.w;
        sd += v.x * b.x + v.y * b.y + v.z * b.z + v.w * b.w;
    }
    als[t] = ss;
    ald[t] = sd;
}

// ======================= CSR build =======================
__global__ void hist_kernel(const int* __restrict__ ei, int* __restrict__ deg) {
    int e = blockIdx.x * blockDim.x + threadIdx.x;
    if (e >= E2_EDGES) return;
    int d = (e < N_EDGES) ? ei[N_EDGES + e] : (e - N_EDGES);
    atomicAdd(deg + d, 1);
}

__global__ __launch_bounds__(256) void scan_block_kernel(const int* __restrict__ deg,
                                                         int* __restrict__ rowptr,
                                                         int* __restrict__ bsum) {
    __shared__ int sdata[256];
    const int b = blockIdx.x, t = threadIdx.x;
    const int base = b * 1024 + t * 4;
    int v[4]; int s = 0;
#pragma unroll
    for (int i = 0; i < 4; i++) {
        int idx = base + i;
        v[i] = (idx < N_NODES) ? deg[idx] : 0;
        s += v[i];
    }
    sdata[t] = s;
    __syncthreads();
    for (int o = 1; o < 256; o <<= 1) {
        int x = (t >= o) ? sdata[t - o] : 0;
        __syncthreads();
        sdata[t] += x;
        __syncthreads();
    }
    if (t == 255) bsum[b] = sdata[255];
    int run = sdata[t] - s;
#pragma unroll
    for (int i = 0; i < 4; i++) {
        int idx = base + i;
        if (idx < N_NODES) rowptr[idx] = run;
        run += v[i];
    }
}

__global__ void scan_bsum_kernel(int* __restrict__ bsum, int nb) {
    if (threadIdx.x == 0 && blockIdx.x == 0) {
        int run = 0;
        for (int i = 0; i < nb; i++) { int v = bsum[i]; bsum[i] = run; run += v; }
    }
}

__global__ void finalize_rowptr_kernel(int* __restrict__ rowptr, const int* __restrict__ bsum,
                                       int* __restrict__ cursor) {
    int i = blockIdx.x * blockDim.x + threadIdx.x;
    if (i >= N_NODES) return;
    int v = rowptr[i] + bsum[i >> 10];
    rowptr[i] = v;
    cursor[i] = v;
}

__global__ void scatter_kernel(const int* __restrict__ ei, int* __restrict__ cursor,
                               int* __restrict__ csr_src) {
    int e = blockIdx.x * blockDim.x + threadIdx.x;
    if (e >= E2_EDGES) return;
    int s, d;
    if (e < N_EDGES) { s = ei[e]; d = ei[N_EDGES + e]; }
    else             { s = d = e - N_EDGES; }
    int pos = atomicAdd(cursor + d, 1);
    csr_src[pos] = s;
}

// ======================= wide GAT agg: 1 wave/node, lane owns 4 ch ===========
// Online softmax, single pass, unroll x2 with prefetch.
template<bool RELU>
__global__ __launch_bounds__(256) void gat_agg_wide_kernel(
    const int* __restrict__ csr_src, const int* __restrict__ rowptr,
    const int* __restrict__ deg, const float* __restrict__ h,
    const float* __restrict__ als, const float* __restrict__ ald,
    const float* __restrict__ bias, float* __restrict__ out, int n) {
    const int lane = threadIdx.x & 63;
    const int node = (blockIdx.x << 2) + (threadIdx.x >> 6);
    if (node >= n) return;
    const int hh = lane >> 4;                  // 4 heads, 16 lanes each
    const int start = rowptr[node];
    const int len = deg[node];
    const float ad = ald[(node << 2) + hh];
    float m = -1e30f, z = 0.f;
    float4 acc = make_float4(0.f, 0.f, 0.f, 0.f);
    int k = 0;
    int s0 = csr_src[start];
    float al0 = als[(s0 << 2) + hh];
    for (; k + 2 <= len; k += 2) {
        int s1 = csr_src[start + k + 1];
        float4 h0 = *(const float4*)(h + ((size_t)s0 << 8) + (lane << 2));
        float al1 = als[(s1 << 2) + hh];
        float4 h1 = *(const float4*)(h + ((size_t)s1 << 8) + (lane << 2));
        int s2 = (k + 2 < len) ? csr_src[start + k + 2] : 0;
        float x0 = al0 + ad; x0 = (x0 > 0.f) ? x0 : 0.2f * x0;
        float x1 = al1 + ad; x1 = (x1 > 0.f) ? x1 : 0.2f * x1;
        float nm = fmaxf(m, fmaxf(x0, x1));
        float c  = __expf(m - nm);
        float p0 = __expf(x0 - nm);
        float p1 = __expf(x1 - nm);
        m = nm;
        z = z * c + p0 + p1;
        acc.x = acc.x * c + p0 * h0.x + p1 * h1.x;
        acc.y = acc.y * c + p0 * h0.y + p1 * h1.y;
        acc.z = acc.z * c + p0 * h0.z + p1 * h1.z;
        acc.w = acc.w * c + p0 * h0.w + p1 * h1.w;
        s0 = s2;
        al0 = als[(s2 << 2) + hh];
    }
    if (k < len) {
        float4 h0 = *(const float4*)(h + ((size_t)s0 << 8) + (lane << 2));
        float x0 = al0 + ad; x0 = (x0 > 0.f) ? x0 : 0.2f * x0;
        float nm = fmaxf(m, x0);
        float c  = __expf(m - nm);
        float p0 = __expf(x0 - nm);
        z = z * c + p0;
        acc.x = acc.x * c + p0 * h0.x;
        acc.y = acc.y * c + p0 * h0.y;
        acc.z = acc.z * c + p0 * h0.z;
        acc.w = acc.w * c + p0 * h0.w;
    }
    float inv = 1.f / (z + 1e-16f);
    float4 bv = *(const float4*)(bias + (lane << 2));
    float4 v;
    v.x = acc.x * inv + bv.x;
    v.y = acc.y * inv + bv.y;
    v.z = acc.z * inv + bv.z;
    v.w = acc.w * inv + bv.w;
    if (RELU) {
        v.x = fmaxf(v.x, 0.f); v.y = fmaxf(v.y, 0.f);
        v.z = fmaxf(v.z, 0.f); v.w = fmaxf(v.w, 0.f);
    }
    *(float4*)(out + ((size_t)node << 8) + (lane << 2)) = v;
}

// ======================= layer-3 agg: H=1, C=64, 1 wave/node, unroll x4 ======
__global__ __launch_bounds__(256) void gat_agg_h1_kernel(
    const int* __restrict__ csr_src, const int* __restrict__ rowptr,
    const int* __restrict__ deg, const float* __restrict__ h,
    const float* __restrict__ als, const float* __restrict__ ald,
    const float* __restrict__ bias, float* __restrict__ out, int n) {
    const int lane = threadIdx.x & 63;
    const int node = (blockIdx.x << 2) + (threadIdx.x >> 6);
    if (node >= n) return;
    const int start = rowptr[node];
    const int len = deg[node];
    const float ad = ald[node];
    float m = -1e30f, z = 0.f, acc = 0.f;
    int k = 0;
    for (; k + 4 <= len; k += 4) {
        int s0 = csr_src[start + k + 0];
        int s1 = csr_src[start + k + 1];
        int s2 = csr_src[start + k + 2];
        int s3 = csr_src[start + k + 3];
        float a0 = als[s0], a1 = als[s1], a2 = als[s2], a3 = als[s3];
        float h0 = h[((size_t)s0 << 6) + lane];
        float h1 = h[((size_t)s1 << 6) + lane];
        float h2 = h[((size_t)s2 << 6) + lane];
        float h3 = h[((size_t)s3 << 6) + lane];
        float x0 = a0 + ad; x0 = (x0 > 0.f) ? x0 : 0.2f * x0;
        float x1 = a1 + ad; x1 = (x1 > 0.f) ? x1 : 0.2f * x1;
        float x2 = a2 + ad; x2 = (x2 > 0.f) ? x2 : 0.2f * x2;
        float x3 = a3 + ad; x3 = (x3 > 0.f) ? x3 : 0.2f * x3;
        float nm = fmaxf(fmaxf(fmaxf(x0, x1), fmaxf(x2, x3)), m);
        float c  = __expf(m - nm);
        float p0 = __expf(x0 - nm), p1 = __expf(x1 - nm);
        float p2 = __expf(x2 - nm), p3 = __expf(x3 - nm);
        m = nm;
        z = z * c + p0 + p1 + p2 + p3;
        acc = acc * c + p0 * h0 + p1 * h1 + p2 * h2 + p3 * h3;
    }
    for (; k < len; k++) {
        int s0 = csr_src[start + k];
        float x0 = als[s0] + ad; x0 = (x0 > 0.f) ? x0 : 0.2f * x0;
        float h0 = h[((size_t)s0 << 6) + lane];
        float nm = fmaxf(m, x0);
        float c  = __expf(m - nm);
        float p0 = __expf(x0 - nm);
        m = nm;
        z = z * c + p0;
        acc = acc * c + p0 * h0;
    }
    out[((size_t)node << 6) + lane] = acc / (z + 1e-16f) + bias[lane];
}

// ---------- mean pooling over (sorted) batch via binary search ----------
__global__ __launch_bounds__(64) void pool_kernel(const float* __restrict__ h3,
                                                  const int* __restrict__ batch,
                                                  float* __restrict__ xg) {
    const int b = blockIdx.x;
    const int j = threadIdx.x;
    int lo = 0, hi = N_NODES;
    while (lo < hi) { int mid = (lo + hi) >> 1; if (batch[mid] < b) lo = mid + 1; else hi = mid; }
    const int start = lo;
    hi = N_NODES;
    while (lo < hi) { int mid = (lo + hi) >> 1; if (batch[mid] < b + 1) lo = mid + 1; else hi = mid; }
    const int end = lo;
    float s = 0.f;
    for (int n = start; n < end; n++) s += h3[(size_t)n * CH + j];
    xg[b * CH + j] = s / fmaxf((float)(end - start), 1.f);
}

// ---------- MLP layer 2 + LayerNorm, one block per graph ----------
__global__ __launch_bounds__(256) void mlp2_ln_kernel(
    const float* __restrict__ y1, const float* __restrict__ Wm2,
    const float* __restrict__ bm2, const float* __restrict__ g2,
    const float* __restrict__ be2, float* __restrict__ out) {
    const int b = blockIdx.x;
    const int j = threadIdx.x;
    __shared__ float yr[NHID];
    yr[j] = y1[(size_t)b * NHID + j];
    __syncthreads();
    float acc = bm2[j];
#pragma unroll 8
    for (int k = 0; k < NHID; k++) acc += yr[k] * Wm2[(size_t)k * NOUT + j];
    float s = acc, s2 = acc * acc;
    for (int o = 32; o > 0; o >>= 1) {
        s += __shfl_down(s, o);
        s2 += __shfl_down(s2, o);
    }
    __shared__ float red[8];
    __shared__ float mv[2];
    int wave = j >> 6, lane = j & 63;
    if (lane == 0) { red[wave] = s; red[4 + wave] = s2; }
    __syncthreads();
    if (j == 0) {
        float ts = red[0] + red[1] + red[2] + red[3];
        float ts2 = red[4] + red[5] + red[6] + red[7];
        float mu = ts / (float)NOUT;
        float var = ts2 / (float)NOUT - mu * mu;
        mv[0] = mu;
        mv[1] = rsqrtf(var + 1e-5f);
    }
    __syncthreads();
    out[(size_t)b * NOUT + j] = (acc - mv[0]) * mv[1] * g2[j] + be2[j];
}

extern "C" void kernel_launch(void* const* d_in, const int* in_sizes, int n_in,
                              void* d_out, int out_size, void* d_ws, size_t ws_size,
                              hipStream_t stream) {
    const float* x      = (const float*)d_in[0];
    const int*   ei     = (const int*)d_in[1];
    const int*   batch  = (const int*)d_in[2];
    const float* W1     = (const float*)d_in[3];
    const float* as1    = (const float*)d_in[4];
    const float* ad1    = (const float*)d_in[5];
    const float* b1     = (const float*)d_in[6];
    const float* W2     = (const float*)d_in[7];
    const float* as2    = (const float*)d_in[8];
    const float* ad2    = (const float*)d_in[9];
    const float* b2     = (const float*)d_in[10];
    const float* W3     = (const float*)d_in[11];
    const float* as3    = (const float*)d_in[12];
    const float* ad3    = (const float*)d_in[13];
    const float* b3     = (const float*)d_in[14];
    const float* Wm1    = (const float*)d_in[15];
    const float* bm1    = (const float*)d_in[16];
    const float* Wm2    = (const float*)d_in[17];
    const float* bm2    = (const float*)d_in[18];
    const float* g2     = (const float*)d_in[19];
    const float* be2    = (const float*)d_in[20];
    float* out = (float*)d_out;

    // workspace layout
    float* bufH = (float*)d_ws;                          // N*HC
    float* bufO = bufH + (size_t)N_NODES * HC;           // N*HC
    float* als  = bufO + (size_t)N_NODES * HC;           // N*HEADS
    float* ald  = als + (size_t)N_NODES * HEADS;         // N*HEADS
    float* xg   = ald + (size_t)N_NODES * HEADS;         // NB*CH
    float* y1   = xg + (size_t)NB * CH;                  // NB*NHID
    int* deg     = (int*)(y1 + (size_t)NB * NHID);       // N
    int* rowptr  = deg + N_NODES;                        // N
    int* cursor  = rowptr + N_NODES;                     // N
    int* bsum    = cursor + N_NODES;                     // cdiv(N,1024)
    int* csr_src = bsum + 64;                            // E2

    const int BLK = 256;
    const int NSCAN = cdiv(N_NODES, 1024);

    // ===================== CSR build (dst-sorted adjacency) =====================
    hipMemsetAsync(deg, 0, (size_t)N_NODES * sizeof(int), stream);
    hist_kernel<<<cdiv(E2_EDGES, BLK), BLK, 0, stream>>>(ei, deg);
    scan_block_kernel<<<NSCAN, 256, 0, stream>>>(deg, rowptr, bsum);
    scan_bsum_kernel<<<1, 64, 0, stream>>>(bsum, NSCAN);
    finalize_rowptr_kernel<<<cdiv(N_NODES, BLK), BLK, 0, stream>>>(rowptr, bsum, cursor);
    scatter_kernel<<<cdiv(E2_EDGES, BLK), BLK, 0, stream>>>(ei, cursor, csr_src);

    // ===================== Layer 1 (F_IN -> H*C) =====================
    lin_kernel<F_IN, HC, 16, 256, false><<<cdiv(N_NODES, 16), 256, 0, stream>>>(
        x, W1, nullptr, bufH, N_NODES);
    attn_logits_kernel<HEADS, CH><<<cdiv((long long)N_NODES * HEADS, BLK), BLK, 0, stream>>>(
        bufH, as1, ad1, als, ald, N_NODES);
    gat_agg_wide_kernel<true><<<cdiv(N_NODES, 4), 256, 0, stream>>>(
        csr_src, rowptr, deg, bufH, als, ald, b1, bufO, N_NODES);

    // ===================== Layer 2 (H*C -> H*C) =====================
    lin_kernel<HC, HC, 16, 256, false><<<cdiv(N_NODES, 16), 256, 0, stream>>>(
        bufO, W2, nullptr, bufH, N_NODES);
    attn_logits_kernel<HEADS, CH><<<cdiv((long long)N_NODES * HEADS, BLK), BLK, 0, stream>>>(
        bufH, as2, ad2, als, ald, N_NODES);
    gat_agg_wide_kernel<true><<<cdiv(N_NODES, 4), 256, 0, stream>>>(
        csr_src, rowptr, deg, bufH, als, ald, b2, bufO, N_NODES);

    // ===================== Layer 3 (H*C -> C, heads=1) =====================
    lin_kernel<HC, CH, 16, 256, false><<<cdiv(N_NODES, 16), 256, 0, stream>>>(
        bufO, W3, nullptr, bufH, N_NODES);
    attn_logits_kernel<1, CH><<<cdiv(N_NODES, BLK), BLK, 0, stream>>>(
        bufH, as3, ad3, als, ald, N_NODES);
    gat_agg_h1_kernel<<<cdiv(N_NODES, 4), 256, 0, stream>>>(
        csr_src, rowptr, deg, bufH, als, ald, b3, bufO, N_NODES);

    // ===================== Mean pooling (batch is sorted) =====================
    pool_kernel<<<NB, 64, 0, stream>>>(bufO, batch, xg);

    // ===================== MLP head + LayerNorm =====================
    lin_kernel<CH, NHID, 16, 256, true><<<cdiv(NB, 16), 256, 0, stream>>>(
        xg, Wm1, bm1, y1, NB);
    mlp2_ln_kernel<<<NB, 256, 0, stream>>>(y1, Wm2, bm2, g2, be2, out);
}

// Round 4
// 562.706 us; speedup vs baseline: 7.9753x; 1.2758x over previous
//
#include <hip/hip_runtime.h>
#include <hip/hip_bf16.h>

#define N_NODES 50000
#define N_EDGES 500000
#define E2_EDGES 550000   // with self loops appended
#define F_IN 32
#define HEADS 4
#define CH 64
#define HC 256            // HEADS*CH
#define NB 1000
#define NHID 256
#define NOUT 256

static inline int cdiv(long long a, long long b) { return (int)((a + b - 1) / b); }

typedef __bf16 bf16x8 __attribute__((ext_vector_type(8)));
typedef unsigned short us8 __attribute__((ext_vector_type(8)));
typedef float f32x4 __attribute__((ext_vector_type(4)));
union BU { us8 u; bf16x8 b; };

// round-to-nearest-even fp32 -> bf16 (bit pattern)
__device__ inline unsigned short f2bf(float f) {
    unsigned u = __float_as_uint(f);
    return (unsigned short)((u + 0x7fffu + ((u >> 16) & 1u)) >> 16);
}
__device__ inline float bf2f(unsigned short h) {
    return __uint_as_float(((unsigned)h) << 16);
}

// ---------- W prep: transpose + split fp32 -> (hi,lo) bf16 ----------
// W is [K][M] row-major; Wt_* are [M][K].
__global__ void wconv_kernel(const float* __restrict__ W,
                             unsigned short* __restrict__ Wt_hi,
                             unsigned short* __restrict__ Wt_lo, int K, int M) {
    int idx = blockIdx.x * blockDim.x + threadIdx.x;
    if (idx >= K * M) return;
    int k = idx / M, m = idx % M;
    float v = W[idx];
    unsigned short hi = f2bf(v);
    Wt_hi[(size_t)m * K + k] = hi;
    Wt_lo[(size_t)m * K + k] = f2bf(v - bf2f(hi));
}

// ---------- MFMA split-bf16 GEMM: C[N,M] = A[N,K] @ W[K,M] ----------
// block = 64 rows x 4 waves; wave w owns rows w*16..w*16+15, all M cols.
template<int K, int M, bool RELU>
__global__ __launch_bounds__(256) void mfma_lin_kernel(
    const float* __restrict__ A, const unsigned short* __restrict__ Wt_hi,
    const unsigned short* __restrict__ Wt_lo, const float* __restrict__ bias,
    float* __restrict__ C, int n_rows) {
    constexpr int NT = M / 16;   // tiles per wave
    constexpr int NCH = K / 32;  // K chunks
    __shared__ unsigned short As_hi[64][32];
    __shared__ unsigned short As_lo[64][32];
    __shared__ unsigned short Ws_hi[M][32];
    __shared__ unsigned short Ws_lo[M][32];
    const int tid = threadIdx.x;
    const int wave = tid >> 6, lane = tid & 63;
    const int quad = lane >> 4, l16 = lane & 15;
    const int row_base = blockIdx.x * 64;
    const int arow = row_base + (tid >> 2);   // A staging: 4 threads/row
    const int acg = (tid & 3) * 8;            // 8-float group within row

    f32x4 acc[NT];
#pragma unroll
    for (int t = 0; t < NT; t++) acc[t] = (f32x4){0.f, 0.f, 0.f, 0.f};

    for (int ch = 0; ch < NCH; ch++) {
        const int k0 = ch * 32;
        // ---- stage A chunk (64 x 32) as hi/lo bf16 ----
        {
            int r = tid >> 2;
            float v[8];
            if (arow < n_rows) {
                const float* ap = A + (size_t)arow * K + k0 + acg;
                float4 f0 = *(const float4*)ap;
                float4 f1 = *(const float4*)(ap + 4);
                v[0] = f0.x; v[1] = f0.y; v[2] = f0.z; v[3] = f0.w;
                v[4] = f1.x; v[5] = f1.y; v[6] = f1.z; v[7] = f1.w;
            } else {
#pragma unroll
                for (int i = 0; i < 8; i++) v[i] = 0.f;
            }
#pragma unroll
            for (int i = 0; i < 8; i++) {
                unsigned short hi = f2bf(v[i]);
                As_hi[r][acg + i] = hi;
                As_lo[r][acg + i] = f2bf(v[i] - bf2f(hi));
            }
        }
        // ---- stage W chunk (M x 32) hi/lo ----
        for (int r = tid; r < M; r += 256) {
            const us8* ph = (const us8*)(Wt_hi + (size_t)r * K + k0);
            const us8* pl = (const us8*)(Wt_lo + (size_t)r * K + k0);
            us8* dh = (us8*)&Ws_hi[r][0];
            us8* dl = (us8*)&Ws_lo[r][0];
#pragma unroll
            for (int i = 0; i < 4; i++) { dh[i] = ph[i]; dl[i] = pl[i]; }
        }
        __syncthreads();
        BU a_hi, a_lo;
        a_hi.u = *(const us8*)&As_hi[wave * 16 + l16][quad * 8];
        a_lo.u = *(const us8*)&As_lo[wave * 16 + l16][quad * 8];
#pragma unroll
        for (int t = 0; t < NT; t++) {
            BU b_hi, b_lo;
            b_hi.u = *(const us8*)&Ws_hi[t * 16 + l16][quad * 8];
            b_lo.u = *(const us8*)&Ws_lo[t * 16 + l16][quad * 8];
            acc[t] = __builtin_amdgcn_mfma_f32_16x16x32_bf16(a_hi.b, b_hi.b, acc[t], 0, 0, 0);
            acc[t] = __builtin_amdgcn_mfma_f32_16x16x32_bf16(a_hi.b, b_lo.b, acc[t], 0, 0, 0);
            acc[t] = __builtin_amdgcn_mfma_f32_16x16x32_bf16(a_lo.b, b_hi.b, acc[t], 0, 0, 0);
        }
        __syncthreads();
    }
    // ---- epilogue: C row = row_base + wave*16 + quad*4 + i, col = t*16 + l16
    const int orow0 = row_base + wave * 16 + quad * 4;
#pragma unroll
    for (int t = 0; t < NT; t++) {
        float bv = bias ? bias[t * 16 + l16] : 0.f;
#pragma unroll
        for (int i = 0; i < 4; i++) {
            int r = orow0 + i;
            if (r < n_rows) {
                float v = acc[t][i] + bv;
                if (RELU) v = fmaxf(v, 0.f);
                C[(size_t)r * M + t * 16 + l16] = v;
            }
        }
    }
}

// ---------- generic small GEMM (still used for MLP layer 1) ----------
template<int K, int M, int TM, int BLOCK, bool RELU>
__global__ __launch_bounds__(BLOCK) void lin_kernel(
    const float* __restrict__ A, const float* __restrict__ W,
    const float* __restrict__ bias, float* __restrict__ C, int n_rows) {
    __shared__ float As[TM][K];
    const int n0 = blockIdx.x * TM;
    const int tid = threadIdx.x;
    for (int idx = tid; idx < TM * K; idx += BLOCK) {
        int r = idx / K, c = idx % K;
        int n = n0 + r;
        As[r][c] = (n < n_rows) ? A[(size_t)n * K + c] : 0.f;
    }
    __syncthreads();
    constexpr int G = BLOCK / M;
    constexpr int RPT = TM / G;
    const int j = tid % M;
    const int g = tid / M;
    float acc[RPT];
#pragma unroll
    for (int i = 0; i < RPT; i++) acc[i] = 0.f;
    for (int k = 0; k < K; k++) {
        float wk = W[(size_t)k * M + j];
#pragma unroll
        for (int i = 0; i < RPT; i++) acc[i] += As[g * RPT + i][k] * wk;
    }
    float bv = bias ? bias[j] : 0.f;
#pragma unroll
    for (int i = 0; i < RPT; i++) {
        int n = n0 + g * RPT + i;
        if (n < n_rows) {
            float v = acc[i] + bv;
            if (RELU) v = fmaxf(v, 0.f);
            C[(size_t)n * M + j] = v;
        }
    }
}

// ---------- per-(node,head) attention logits (float4 loads) ----------
template<int H_, int C_>
__global__ void attn_logits_kernel(const float* __restrict__ h,
                                   const float* __restrict__ a_src,
                                   const float* __restrict__ a_dst,
                                   float* __restrict__ als, float* __restrict__ ald,
                                   int n) {
    int t = blockIdx.x * blockDim.x + threadIdx.x;
    if (t >= n * H_) return;
    int node = t / H_, hh = t % H_;
    const float4* hp = (const float4*)(h + (size_t)node * (H_ * C_) + hh * C_);
    const float4* as = (const float4*)(a_src + hh * C_);
    const float4* ad = (const float4*)(a_dst + hh * C_);
    float ss = 0.f, sd = 0.f;
#pragma unroll
    for (int c = 0; c < C_ / 4; c++) {
        float4 v = hp[c], a = as[c], b = ad[c];
        ss += v.x * a.x + v.y * a.y + v.z * a.z + v.w * a.w;
        sd += v.x * b.x + v.y * b.y + v.z * b.z + v.w * b.w;
    }
    als[t] = ss;
    ald[t] = sd;
}

// ======================= CSR build =======================
__global__ void hist_kernel(const int* __restrict__ ei, int* __restrict__ deg) {
    int e = blockIdx.x * blockDim.x + threadIdx.x;
    if (e >= E2_EDGES) return;
    int d = (e < N_EDGES) ? ei[N_EDGES + e] : (e - N_EDGES);
    atomicAdd(deg + d, 1);
}

__global__ __launch_bounds__(256) void scan_block_kernel(const int* __restrict__ deg,
                                                         int* __restrict__ rowptr,
                                                         int* __restrict__ bsum) {
    __shared__ int sdata[256];
    const int b = blockIdx.x, t = threadIdx.x;
    const int base = b * 1024 + t * 4;
    int v[4]; int s = 0;
#pragma unroll
    for (int i = 0; i < 4; i++) {
        int idx = base + i;
        v[i] = (idx < N_NODES) ? deg[idx] : 0;
        s += v[i];
    }
    sdata[t] = s;
    __syncthreads();
    for (int o = 1; o < 256; o <<= 1) {
        int x = (t >= o) ? sdata[t - o] : 0;
        __syncthreads();
        sdata[t] += x;
        __syncthreads();
    }
    if (t == 255) bsum[b] = sdata[255];
    int run = sdata[t] - s;
#pragma unroll
    for (int i = 0; i < 4; i++) {
        int idx = base + i;
        if (idx < N_NODES) rowptr[idx] = run;
        run += v[i];
    }
}

__global__ void scan_bsum_kernel(int* __restrict__ bsum, int nb) {
    if (threadIdx.x == 0 && blockIdx.x == 0) {
        int run = 0;
        for (int i = 0; i < nb; i++) { int v = bsum[i]; bsum[i] = run; run += v; }
    }
}

__global__ void finalize_rowptr_kernel(int* __restrict__ rowptr, const int* __restrict__ bsum,
                                       int* __restrict__ cursor) {
    int i = blockIdx.x * blockDim.x + threadIdx.x;
    if (i >= N_NODES) return;
    int v = rowptr[i] + bsum[i >> 10];
    rowptr[i] = v;
    cursor[i] = v;
}

__global__ void scatter_kernel(const int* __restrict__ ei, int* __restrict__ cursor,
                               int* __restrict__ csr_src) {
    int e = blockIdx.x * blockDim.x + threadIdx.x;
    if (e >= E2_EDGES) return;
    int s, d;
    if (e < N_EDGES) { s = ei[e]; d = ei[N_EDGES + e]; }
    else             { s = d = e - N_EDGES; }
    int pos = atomicAdd(cursor + d, 1);
    csr_src[pos] = s;
}

// ======================= wide GAT agg: 1 wave/node, lane owns 4 ch ===========
template<bool RELU>
__global__ __launch_bounds__(256) void gat_agg_wide_kernel(
    const int* __restrict__ csr_src, const int* __restrict__ rowptr,
    const int* __restrict__ deg, const float* __restrict__ h,
    const float* __restrict__ als, const float* __restrict__ ald,
    const float* __restrict__ bias, float* __restrict__ out, int n) {
    const int lane = threadIdx.x & 63;
    const int node = (blockIdx.x << 2) + (threadIdx.x >> 6);
    if (node >= n) return;
    const int hh = lane >> 4;
    const int start = rowptr[node];
    const int len = deg[node];
    const float ad = ald[(node << 2) + hh];
    float m = -1e30f, z = 0.f;
    float4 acc = make_float4(0.f, 0.f, 0.f, 0.f);
    int k = 0;
    int s0 = csr_src[start];
    float al0 = als[(s0 << 2) + hh];
    for (; k + 2 <= len; k += 2) {
        int s1 = csr_src[start + k + 1];
        float4 h0 = *(const float4*)(h + ((size_t)s0 << 8) + (lane << 2));
        float al1 = als[(s1 << 2) + hh];
        float4 h1 = *(const float4*)(h + ((size_t)s1 << 8) + (lane << 2));
        int s2 = (k + 2 < len) ? csr_src[start + k + 2] : 0;
        float x0 = al0 + ad; x0 = (x0 > 0.f) ? x0 : 0.2f * x0;
        float x1 = al1 + ad; x1 = (x1 > 0.f) ? x1 : 0.2f * x1;
        float nm = fmaxf(m, fmaxf(x0, x1));
        float c  = __expf(m - nm);
        float p0 = __expf(x0 - nm);
        float p1 = __expf(x1 - nm);
        m = nm;
        z = z * c + p0 + p1;
        acc.x = acc.x * c + p0 * h0.x + p1 * h1.x;
        acc.y = acc.y * c + p0 * h0.y + p1 * h1.y;
        acc.z = acc.z * c + p0 * h0.z + p1 * h1.z;
        acc.w = acc.w * c + p0 * h0.w + p1 * h1.w;
        s0 = s2;
        al0 = als[(s2 << 2) + hh];
    }
    if (k < len) {
        float4 h0 = *(const float4*)(h + ((size_t)s0 << 8) + (lane << 2));
        float x0 = al0 + ad; x0 = (x0 > 0.f) ? x0 : 0.2f * x0;
        float nm = fmaxf(m, x0);
        float c  = __expf(m - nm);
        float p0 = __expf(x0 - nm);
        z = z * c + p0;
        acc.x = acc.x * c + p0 * h0.x;
        acc.y = acc.y * c + p0 * h0.y;
        acc.z = acc.z * c + p0 * h0.z;
        acc.w = acc.w * c + p0 * h0.w;
    }
    float inv = 1.f / (z + 1e-16f);
    float4 bv = *(const float4*)(bias + (lane << 2));
    float4 v;
    v.x = acc.x * inv + bv.x;
    v.y = acc.y * inv + bv.y;
    v.z = acc.z * inv + bv.z;
    v.w = acc.w * inv + bv.w;
    if (RELU) {
        v.x = fmaxf(v.x, 0.f); v.y = fmaxf(v.y, 0.f);
        v.z = fmaxf(v.z, 0.f); v.w = fmaxf(v.w, 0.f);
    }
    *(float4*)(out + ((size_t)node << 8) + (lane << 2)) = v;
}

// ======================= layer-3 agg: H=1, C=64 ======
__global__ __launch_bounds__(256) void gat_agg_h1_kernel(
    const int* __restrict__ csr_src, const int* __restrict__ rowptr,
    const int* __restrict__ deg, const float* __restrict__ h,
    const float* __restrict__ als, const float* __restrict__ ald,
    const float* __restrict__ bias, float* __restrict__ out, int n) {
    const int lane = threadIdx.x & 63;
    const int node = (blockIdx.x << 2) + (threadIdx.x >> 6);
    if (node >= n) return;
    const int start = rowptr[node];
    const int len = deg[node];
    const float ad = ald[node];
    float m = -1e30f, z = 0.f, acc = 0.f;
    int k = 0;
    for (; k + 4 <= len; k += 4) {
        int s0 = csr_src[start + k + 0];
        int s1 = csr_src[start + k + 1];
        int s2 = csr_src[start + k + 2];
        int s3 = csr_src[start + k + 3];
        float a0 = als[s0], a1 = als[s1], a2 = als[s2], a3 = als[s3];
        float h0 = h[((size_t)s0 << 6) + lane];
        float h1 = h[((size_t)s1 << 6) + lane];
        float h2 = h[((size_t)s2 << 6) + lane];
        float h3 = h[((size_t)s3 << 6) + lane];
        float x0 = a0 + ad; x0 = (x0 > 0.f) ? x0 : 0.2f * x0;
        float x1 = a1 + ad; x1 = (x1 > 0.f) ? x1 : 0.2f * x1;
        float x2 = a2 + ad; x2 = (x2 > 0.f) ? x2 : 0.2f * x2;
        float x3 = a3 + ad; x3 = (x3 > 0.f) ? x3 : 0.2f * x3;
        float nm = fmaxf(fmaxf(fmaxf(x0, x1), fmaxf(x2, x3)), m);
        float c  = __expf(m - nm);
        float p0 = __expf(x0 - nm), p1 = __expf(x1 - nm);
        float p2 = __expf(x2 - nm), p3 = __expf(x3 - nm);
        m = nm;
        z = z * c + p0 + p1 + p2 + p3;
        acc = acc * c + p0 * h0 + p1 * h1 + p2 * h2 + p3 * h3;
    }
    for (; k < len; k++) {
        int s0 = csr_src[start + k];
        float x0 = als[s0] + ad; x0 = (x0 > 0.f) ? x0 : 0.2f * x0;
        float h0 = h[((size_t)s0 << 6) + lane];
        float nm = fmaxf(m, x0);
        float c  = __expf(m - nm);
        float p0 = __expf(x0 - nm);
        m = nm;
        z = z * c + p0;
        acc = acc * c + p0 * h0;
    }
    out[((size_t)node << 6) + lane] = acc / (z + 1e-16f) + bias[lane];
}

// ---------- mean pooling over (sorted) batch via binary search ----------
__global__ __launch_bounds__(64) void pool_kernel(const float* __restrict__ h3,
                                                  const int* __restrict__ batch,
                                                  float* __restrict__ xg) {
    const int b = blockIdx.x;
    const int j = threadIdx.x;
    int lo = 0, hi = N_NODES;
    while (lo < hi) { int mid = (lo + hi) >> 1; if (batch[mid] < b) lo = mid + 1; else hi = mid; }
    const int start = lo;
    hi = N_NODES;
    while (lo < hi) { int mid = (lo + hi) >> 1; if (batch[mid] < b + 1) lo = mid + 1; else hi = mid; }
    const int end = lo;
    float s = 0.f;
    for (int n = start; n < end; n++) s += h3[(size_t)n * CH + j];
    xg[b * CH + j] = s / fmaxf((float)(end - start), 1.f);
}

// ---------- MLP layer 2 + LayerNorm, one block per graph ----------
__global__ __launch_bounds__(256) void mlp2_ln_kernel(
    const float* __restrict__ y1, const float* __restrict__ Wm2,
    const float* __restrict__ bm2, const float* __restrict__ g2,
    const float* __restrict__ be2, float* __restrict__ out) {
    const int b = blockIdx.x;
    const int j = threadIdx.x;
    __shared__ float yr[NHID];
    yr[j] = y1[(size_t)b * NHID + j];
    __syncthreads();
    float acc = bm2[j];
#pragma unroll 8
    for (int k = 0; k < NHID; k++) acc += yr[k] * Wm2[(size_t)k * NOUT + j];
    float s = acc, s2 = acc * acc;
    for (int o = 32; o > 0; o >>= 1) {
        s += __shfl_down(s, o);
        s2 += __shfl_down(s2, o);
    }
    __shared__ float red[8];
    __shared__ float mv[2];
    int wave = j >> 6, lane = j & 63;
    if (lane == 0) { red[wave] = s; red[4 + wave] = s2; }
    __syncthreads();
    if (j == 0) {
        float ts = red[0] + red[1] + red[2] + red[3];
        float ts2 = red[4] + red[5] + red[6] + red[7];
        float mu = ts / (float)NOUT;
        float var = ts2 / (float)NOUT - mu * mu;
        mv[0] = mu;
        mv[1] = rsqrtf(var + 1e-5f);
    }
    __syncthreads();
    out[(size_t)b * NOUT + j] = (acc - mv[0]) * mv[1] * g2[j] + be2[j];
}

extern "C" void kernel_launch(void* const* d_in, const int* in_sizes, int n_in,
                              void* d_out, int out_size, void* d_ws, size_t ws_size,
                              hipStream_t stream) {
    const float* x      = (const float*)d_in[0];
    const int*   ei     = (const int*)d_in[1];
    const int*   batch  = (const int*)d_in[2];
    const float* W1     = (const float*)d_in[3];
    const float* as1    = (const float*)d_in[4];
    const float* ad1    = (const float*)d_in[5];
    const float* b1     = (const float*)d_in[6];
    const float* W2     = (const float*)d_in[7];
    const float* as2    = (const float*)d_in[8];
    const float* ad2    = (const float*)d_in[9];
    const float* b2     = (const float*)d_in[10];
    const float* W3     = (const float*)d_in[11];
    const float* as3    = (const float*)d_in[12];
    const float* ad3    = (const float*)d_in[13];
    const float* b3     = (const float*)d_in[14];
    const float* Wm1    = (const float*)d_in[15];
    const float* bm1    = (const float*)d_in[16];
    const float* Wm2    = (const float*)d_in[17];
    const float* bm2    = (const float*)d_in[18];
    const float* g2     = (const float*)d_in[19];
    const float* be2    = (const float*)d_in[20];
    float* out = (float*)d_out;

    // workspace layout
    float* bufH = (float*)d_ws;                          // N*HC
    float* bufO = bufH + (size_t)N_NODES * HC;           // N*HC
    float* als  = bufO + (size_t)N_NODES * HC;           // N*HEADS
    float* ald  = als + (size_t)N_NODES * HEADS;         // N*HEADS
    float* xg   = ald + (size_t)N_NODES * HEADS;         // NB*CH
    float* y1   = xg + (size_t)NB * CH;                  // NB*NHID
    int* deg     = (int*)(y1 + (size_t)NB * NHID);       // N
    int* rowptr  = deg + N_NODES;                        // N
    int* cursor  = rowptr + N_NODES;                     // N
    int* bsum    = cursor + N_NODES;                     // cdiv(N,1024) <= 64
    int* csr_src = bsum + 64;                            // E2
    unsigned short* wt1h = (unsigned short*)(csr_src + E2_EDGES);  // 256*32
    unsigned short* wt1l = wt1h + 256 * 32;
    unsigned short* wt2h = wt1l + 256 * 32;                        // 256*256
    unsigned short* wt2l = wt2h + 256 * 256;
    unsigned short* wt3h = wt2l + 256 * 256;                       // 64*256
    unsigned short* wt3l = wt3h + 64 * 256;

    const int BLK = 256;
    const int NSCAN = cdiv(N_NODES, 1024);

    // ===================== weight prep (split bf16, transposed) ==============
    wconv_kernel<<<cdiv(F_IN * HC, BLK), BLK, 0, stream>>>(W1, wt1h, wt1l, F_IN, HC);
    wconv_kernel<<<cdiv(HC * HC, BLK), BLK, 0, stream>>>(W2, wt2h, wt2l, HC, HC);
    wconv_kernel<<<cdiv(HC * CH, BLK), BLK, 0, stream>>>(W3, wt3h, wt3l, HC, CH);

    // ===================== CSR build (dst-sorted adjacency) =====================
    hipMemsetAsync(deg, 0, (size_t)N_NODES * sizeof(int), stream);
    hist_kernel<<<cdiv(E2_EDGES, BLK), BLK, 0, stream>>>(ei, deg);
    scan_block_kernel<<<NSCAN, 256, 0, stream>>>(deg, rowptr, bsum);
    scan_bsum_kernel<<<1, 64, 0, stream>>>(bsum, NSCAN);
    finalize_rowptr_kernel<<<cdiv(N_NODES, BLK), BLK, 0, stream>>>(rowptr, bsum, cursor);
    scatter_kernel<<<cdiv(E2_EDGES, BLK), BLK, 0, stream>>>(ei, cursor, csr_src);

    // ===================== Layer 1 (F_IN -> H*C) =====================
    mfma_lin_kernel<F_IN, HC, false><<<cdiv(N_NODES, 64), 256, 0, stream>>>(
        x, wt1h, wt1l, nullptr, bufH, N_NODES);
    attn_logits_kernel<HEADS, CH><<<cdiv((long long)N_NODES * HEADS, BLK), BLK, 0, stream>>>(
        bufH, as1, ad1, als, ald, N_NODES);
    gat_agg_wide_kernel<true><<<cdiv(N_NODES, 4), 256, 0, stream>>>(
        csr_src, rowptr, deg, bufH, als, ald, b1, bufO, N_NODES);

    // ===================== Layer 2 (H*C -> H*C) =====================
    mfma_lin_kernel<HC, HC, false><<<cdiv(N_NODES, 64), 256, 0, stream>>>(
        bufO, wt2h, wt2l, nullptr, bufH, N_NODES);
    attn_logits_kernel<HEADS, CH><<<cdiv((long long)N_NODES * HEADS, BLK), BLK, 0, stream>>>(
        bufH, as2, ad2, als, ald, N_NODES);
    gat_agg_wide_kernel<true><<<cdiv(N_NODES, 4), 256, 0, stream>>>(
        csr_src, rowptr, deg, bufH, als, ald, b2, bufO, N_NODES);

    // ===================== Layer 3 (H*C -> C, heads=1) =====================
    mfma_lin_kernel<HC, CH, false><<<cdiv(N_NODES, 64), 256, 0, stream>>>(
        bufO, wt3h, wt3l, nullptr, bufH, N_NODES);
    attn_logits_kernel<1, CH><<<cdiv(N_NODES, BLK), BLK, 0, stream>>>(
        bufH, as3, ad3, als, ald, N_NODES);
    gat_agg_h1_kernel<<<cdiv(N_NODES, 4), 256, 0, stream>>>(
        csr_src, rowptr, deg, bufH, als, ald, b3, bufO, N_NODES);

    // ===================== Mean pooling (batch is sorted) =====================
    pool_kernel<<<NB, 64, 0, stream>>>(bufO, batch, xg);

    // ===================== MLP head + LayerNorm =====================
    lin_kernel<CH, NHID, 16, 256, true><<<cdiv(NB, 16), 256, 0, stream>>>(
        xg, Wm1, bm1, y1, NB);
    mlp2_ln_kernel<<<NB, 256, 0, stream>>>(y1, Wm2, bm2, g2, be2, out);
}

// Round 5
// 484.448 us; speedup vs baseline: 9.2637x; 1.1615x over previous
//
#include <hip/hip_runtime.h>
#include <hip/hip_bf16.h>

#define N_NODES 50000
#define N_EDGES 500000
#define E2_EDGES 550000   // with self loops appended
#define F_IN 32
#define HEADS 4
#define CH 64
#define HC 256            // HEADS*CH
#define NB 1000
#define NHID 256
#define NOUT 256

static inline int cdiv(long long a, long long b) { return (int)((a + b - 1) / b); }

typedef __bf16 bf16x8 __attribute__((ext_vector_type(8)));
typedef unsigned short us8 __attribute__((ext_vector_type(8)));
typedef unsigned short us4 __attribute__((ext_vector_type(4)));
typedef float f32x4 __attribute__((ext_vector_type(4)));
union BU { us8 u; bf16x8 b; };

// round-to-nearest-even fp32 -> bf16 (bit pattern)
__device__ inline unsigned short f2bf(float f) {
    unsigned u = __float_as_uint(f);
    return (unsigned short)((u + 0x7fffu + ((u >> 16) & 1u)) >> 16);
}
__device__ inline float bf2f(unsigned short h) {
    return __uint_as_float(((unsigned)h) << 16);
}

// ---------- W prep: transpose + split fp32 -> (hi,lo) bf16 ----------
__global__ void wconv_kernel(const float* __restrict__ W,
                             unsigned short* __restrict__ Wt_hi,
                             unsigned short* __restrict__ Wt_lo, int K, int M) {
    int idx = blockIdx.x * blockDim.x + threadIdx.x;
    if (idx >= K * M) return;
    int k = idx / M, m = idx % M;
    float v = W[idx];
    unsigned short hi = f2bf(v);
    Wt_hi[(size_t)m * K + k] = hi;
    Wt_lo[(size_t)m * K + k] = f2bf(v - bf2f(hi));
}

// ---------- MFMA split-bf16 GEMM: C[N,M] = A[N,K] @ W[K,M] ----------
// OBF: write output as bf16 (for gather-heavy h buffers) else fp32.
template<int K, int M, bool RELU, bool OBF>
__global__ __launch_bounds__(256) void mfma_lin_kernel(
    const float* __restrict__ A, const unsigned short* __restrict__ Wt_hi,
    const unsigned short* __restrict__ Wt_lo, const float* __restrict__ bias,
    void* __restrict__ Cout, int n_rows) {
    constexpr int NT = M / 16;   // tiles per wave
    constexpr int NCH = K / 32;  // K chunks
    __shared__ unsigned short As_hi[64][32];
    __shared__ unsigned short As_lo[64][32];
    __shared__ unsigned short Ws_hi[M][32];
    __shared__ unsigned short Ws_lo[M][32];
    const int tid = threadIdx.x;
    const int wave = tid >> 6, lane = tid & 63;
    const int quad = lane >> 4, l16 = lane & 15;
    const int row_base = blockIdx.x * 64;
    const int arow = row_base + (tid >> 2);
    const int acg = (tid & 3) * 8;

    f32x4 acc[NT];
#pragma unroll
    for (int t = 0; t < NT; t++) acc[t] = (f32x4){0.f, 0.f, 0.f, 0.f};

    for (int ch = 0; ch < NCH; ch++) {
        const int k0 = ch * 32;
        {
            int r = tid >> 2;
            float v[8];
            if (arow < n_rows) {
                const float* ap = A + (size_t)arow * K + k0 + acg;
                float4 f0 = *(const float4*)ap;
                float4 f1 = *(const float4*)(ap + 4);
                v[0] = f0.x; v[1] = f0.y; v[2] = f0.z; v[3] = f0.w;
                v[4] = f1.x; v[5] = f1.y; v[6] = f1.z; v[7] = f1.w;
            } else {
#pragma unroll
                for (int i = 0; i < 8; i++) v[i] = 0.f;
            }
#pragma unroll
            for (int i = 0; i < 8; i++) {
                unsigned short hi = f2bf(v[i]);
                As_hi[r][acg + i] = hi;
                As_lo[r][acg + i] = f2bf(v[i] - bf2f(hi));
            }
        }
        for (int r = tid; r < M; r += 256) {
            const us8* ph = (const us8*)(Wt_hi + (size_t)r * K + k0);
            const us8* pl = (const us8*)(Wt_lo + (size_t)r * K + k0);
            us8* dh = (us8*)&Ws_hi[r][0];
            us8* dl = (us8*)&Ws_lo[r][0];
#pragma unroll
            for (int i = 0; i < 4; i++) { dh[i] = ph[i]; dl[i] = pl[i]; }
        }
        __syncthreads();
        BU a_hi, a_lo;
        a_hi.u = *(const us8*)&As_hi[wave * 16 + l16][quad * 8];
        a_lo.u = *(const us8*)&As_lo[wave * 16 + l16][quad * 8];
#pragma unroll
        for (int t = 0; t < NT; t++) {
            BU b_hi, b_lo;
            b_hi.u = *(const us8*)&Ws_hi[t * 16 + l16][quad * 8];
            b_lo.u = *(const us8*)&Ws_lo[t * 16 + l16][quad * 8];
            acc[t] = __builtin_amdgcn_mfma_f32_16x16x32_bf16(a_hi.b, b_hi.b, acc[t], 0, 0, 0);
            acc[t] = __builtin_amdgcn_mfma_f32_16x16x32_bf16(a_hi.b, b_lo.b, acc[t], 0, 0, 0);
            acc[t] = __builtin_amdgcn_mfma_f32_16x16x32_bf16(a_lo.b, b_hi.b, acc[t], 0, 0, 0);
        }
        __syncthreads();
    }
    const int orow0 = row_base + wave * 16 + quad * 4;
#pragma unroll
    for (int t = 0; t < NT; t++) {
        float bv = bias ? bias[t * 16 + l16] : 0.f;
#pragma unroll
        for (int i = 0; i < 4; i++) {
            int r = orow0 + i;
            if (r < n_rows) {
                float v = acc[t][i] + bv;
                if (RELU) v = fmaxf(v, 0.f);
                if (OBF) ((unsigned short*)Cout)[(size_t)r * M + t * 16 + l16] = f2bf(v);
                else     ((float*)Cout)[(size_t)r * M + t * 16 + l16] = v;
            }
        }
    }
}

// ---------- generic small GEMM (MLP layer 1) ----------
template<int K, int M, int TM, int BLOCK, bool RELU>
__global__ __launch_bounds__(BLOCK) void lin_kernel(
    const float* __restrict__ A, const float* __restrict__ W,
    const float* __restrict__ bias, float* __restrict__ C, int n_rows) {
    __shared__ float As[TM][K];
    const int n0 = blockIdx.x * TM;
    const int tid = threadIdx.x;
    for (int idx = tid; idx < TM * K; idx += BLOCK) {
        int r = idx / K, c = idx % K;
        int n = n0 + r;
        As[r][c] = (n < n_rows) ? A[(size_t)n * K + c] : 0.f;
    }
    __syncthreads();
    constexpr int G = BLOCK / M;
    constexpr int RPT = TM / G;
    const int j = tid % M;
    const int g = tid / M;
    float acc[RPT];
#pragma unroll
    for (int i = 0; i < RPT; i++) acc[i] = 0.f;
    for (int k = 0; k < K; k++) {
        float wk = W[(size_t)k * M + j];
#pragma unroll
        for (int i = 0; i < RPT; i++) acc[i] += As[g * RPT + i][k] * wk;
    }
    float bv = bias ? bias[j] : 0.f;
#pragma unroll
    for (int i = 0; i < RPT; i++) {
        int n = n0 + g * RPT + i;
        if (n < n_rows) {
            float v = acc[i] + bv;
            if (RELU) v = fmaxf(v, 0.f);
            C[(size_t)n * M + j] = v;
        }
    }
}

// ---------- per-(node,head) attention logits from bf16 h ----------
template<int H_, int C_>
__global__ void attn_logits_kernel(const unsigned short* __restrict__ h,
                                   const float* __restrict__ a_src,
                                   const float* __restrict__ a_dst,
                                   float* __restrict__ als, float* __restrict__ ald,
                                   int n) {
    int t = blockIdx.x * blockDim.x + threadIdx.x;
    if (t >= n * H_) return;
    int node = t / H_, hh = t % H_;
    const us8* hp = (const us8*)(h + (size_t)node * (H_ * C_) + hh * C_);
    const float4* as = (const float4*)(a_src + hh * C_);
    const float4* ad = (const float4*)(a_dst + hh * C_);
    float ss = 0.f, sd = 0.f;
#pragma unroll
    for (int c = 0; c < C_ / 8; c++) {
        us8 hv = hp[c];
        float4 a0 = as[2 * c], a1 = as[2 * c + 1];
        float4 b0 = ad[2 * c], b1 = ad[2 * c + 1];
        float f0 = bf2f(hv[0]), f1 = bf2f(hv[1]), f2 = bf2f(hv[2]), f3 = bf2f(hv[3]);
        float f4 = bf2f(hv[4]), f5 = bf2f(hv[5]), f6 = bf2f(hv[6]), f7 = bf2f(hv[7]);
        ss += f0 * a0.x + f1 * a0.y + f2 * a0.z + f3 * a0.w
            + f4 * a1.x + f5 * a1.y + f6 * a1.z + f7 * a1.w;
        sd += f0 * b0.x + f1 * b0.y + f2 * b0.z + f3 * b0.w
            + f4 * b1.x + f5 * b1.y + f6 * b1.z + f7 * b1.w;
    }
    als[t] = ss;
    ald[t] = sd;
}

// ======================= CSR build =======================
__global__ void hist_kernel(const int* __restrict__ ei, int* __restrict__ deg) {
    int e = blockIdx.x * blockDim.x + threadIdx.x;
    if (e >= E2_EDGES) return;
    int d = (e < N_EDGES) ? ei[N_EDGES + e] : (e - N_EDGES);
    atomicAdd(deg + d, 1);
}

__global__ __launch_bounds__(256) void scan_block_kernel(const int* __restrict__ deg,
                                                         int* __restrict__ rowptr,
                                                         int* __restrict__ bsum) {
    __shared__ int sdata[256];
    const int b = blockIdx.x, t = threadIdx.x;
    const int base = b * 1024 + t * 4;
    int v[4]; int s = 0;
#pragma unroll
    for (int i = 0; i < 4; i++) {
        int idx = base + i;
        v[i] = (idx < N_NODES) ? deg[idx] : 0;
        s += v[i];
    }
    sdata[t] = s;
    __syncthreads();
    for (int o = 1; o < 256; o <<= 1) {
        int x = (t >= o) ? sdata[t - o] : 0;
        __syncthreads();
        sdata[t] += x;
        __syncthreads();
    }
    if (t == 255) bsum[b] = sdata[255];
    int run = sdata[t] - s;
#pragma unroll
    for (int i = 0; i < 4; i++) {
        int idx = base + i;
        if (idx < N_NODES) rowptr[idx] = run;
        run += v[i];
    }
}

__global__ void scan_bsum_kernel(int* __restrict__ bsum, int nb) {
    if (threadIdx.x == 0 && blockIdx.x == 0) {
        int run = 0;
        for (int i = 0; i < nb; i++) { int v = bsum[i]; bsum[i] = run; run += v; }
    }
}

__global__ void finalize_rowptr_kernel(int* __restrict__ rowptr, const int* __restrict__ bsum,
                                       int* __restrict__ cursor) {
    int i = blockIdx.x * blockDim.x + threadIdx.x;
    if (i >= N_NODES) return;
    int v = rowptr[i] + bsum[i >> 10];
    rowptr[i] = v;
    cursor[i] = v;
}

__global__ void scatter_kernel(const int* __restrict__ ei, int* __restrict__ cursor,
                               int* __restrict__ csr_src) {
    int e = blockIdx.x * blockDim.x + threadIdx.x;
    if (e >= E2_EDGES) return;
    int s, d;
    if (e < N_EDGES) { s = ei[e]; d = ei[N_EDGES + e]; }
    else             { s = d = e - N_EDGES; }
    int pos = atomicAdd(cursor + d, 1);
    csr_src[pos] = s;
}

// ======================= wide GAT agg: 1 wave/node, lane owns 4 ch (bf16 h) ==
template<bool RELU>
__global__ __launch_bounds__(256) void gat_agg_wide_kernel(
    const int* __restrict__ csr_src, const int* __restrict__ rowptr,
    const int* __restrict__ deg, const unsigned short* __restrict__ h,
    const float* __restrict__ als, const float* __restrict__ ald,
    const float* __restrict__ bias, float* __restrict__ out, int n) {
    const int lane = threadIdx.x & 63;
    const int node = (blockIdx.x << 2) + (threadIdx.x >> 6);
    if (node >= n) return;
    const int hh = lane >> 4;
    const int start = rowptr[node];
    const int len = deg[node];
    const float ad = ald[(node << 2) + hh];
    float m = -1e30f, z = 0.f;
    float4 acc = make_float4(0.f, 0.f, 0.f, 0.f);
    int k = 0;
    for (; k + 4 <= len; k += 4) {
        int s0 = csr_src[start + k + 0];
        int s1 = csr_src[start + k + 1];
        int s2 = csr_src[start + k + 2];
        int s3 = csr_src[start + k + 3];
        float a0 = als[(s0 << 2) + hh], a1 = als[(s1 << 2) + hh];
        float a2 = als[(s2 << 2) + hh], a3 = als[(s3 << 2) + hh];
        us4 h0 = *(const us4*)(h + ((size_t)s0 << 8) + (lane << 2));
        us4 h1 = *(const us4*)(h + ((size_t)s1 << 8) + (lane << 2));
        us4 h2 = *(const us4*)(h + ((size_t)s2 << 8) + (lane << 2));
        us4 h3 = *(const us4*)(h + ((size_t)s3 << 8) + (lane << 2));
        float x0 = a0 + ad; x0 = (x0 > 0.f) ? x0 : 0.2f * x0;
        float x1 = a1 + ad; x1 = (x1 > 0.f) ? x1 : 0.2f * x1;
        float x2 = a2 + ad; x2 = (x2 > 0.f) ? x2 : 0.2f * x2;
        float x3 = a3 + ad; x3 = (x3 > 0.f) ? x3 : 0.2f * x3;
        float nm = fmaxf(fmaxf(fmaxf(x0, x1), fmaxf(x2, x3)), m);
        float c  = __expf(m - nm);
        float p0 = __expf(x0 - nm), p1 = __expf(x1 - nm);
        float p2 = __expf(x2 - nm), p3 = __expf(x3 - nm);
        m = nm;
        z = z * c + p0 + p1 + p2 + p3;
        acc.x = acc.x * c + p0 * bf2f(h0[0]) + p1 * bf2f(h1[0]) + p2 * bf2f(h2[0]) + p3 * bf2f(h3[0]);
        acc.y = acc.y * c + p0 * bf2f(h0[1]) + p1 * bf2f(h1[1]) + p2 * bf2f(h2[1]) + p3 * bf2f(h3[1]);
        acc.z = acc.z * c + p0 * bf2f(h0[2]) + p1 * bf2f(h1[2]) + p2 * bf2f(h2[2]) + p3 * bf2f(h3[2]);
        acc.w = acc.w * c + p0 * bf2f(h0[3]) + p1 * bf2f(h1[3]) + p2 * bf2f(h2[3]) + p3 * bf2f(h3[3]);
    }
    for (; k < len; k++) {
        int s0 = csr_src[start + k];
        float x0 = als[(s0 << 2) + hh] + ad; x0 = (x0 > 0.f) ? x0 : 0.2f * x0;
        us4 h0 = *(const us4*)(h + ((size_t)s0 << 8) + (lane << 2));
        float nm = fmaxf(m, x0);
        float c  = __expf(m - nm);
        float p0 = __expf(x0 - nm);
        m = nm;
        z = z * c + p0;
        acc.x = acc.x * c + p0 * bf2f(h0[0]);
        acc.y = acc.y * c + p0 * bf2f(h0[1]);
        acc.z = acc.z * c + p0 * bf2f(h0[2]);
        acc.w = acc.w * c + p0 * bf2f(h0[3]);
    }
    float inv = 1.f / (z + 1e-16f);
    float4 bv = *(const float4*)(bias + (lane << 2));
    float4 v;
    v.x = acc.x * inv + bv.x;
    v.y = acc.y * inv + bv.y;
    v.z = acc.z * inv + bv.z;
    v.w = acc.w * inv + bv.w;
    if (RELU) {
        v.x = fmaxf(v.x, 0.f); v.y = fmaxf(v.y, 0.f);
        v.z = fmaxf(v.z, 0.f); v.w = fmaxf(v.w, 0.f);
    }
    *(float4*)(out + ((size_t)node << 8) + (lane << 2)) = v;
}

// ======================= layer-3 agg: H=1, C=64 (bf16 h) ======
__global__ __launch_bounds__(256) void gat_agg_h1_kernel(
    const int* __restrict__ csr_src, const int* __restrict__ rowptr,
    const int* __restrict__ deg, const unsigned short* __restrict__ h,
    const float* __restrict__ als, const float* __restrict__ ald,
    const float* __restrict__ bias, float* __restrict__ out, int n) {
    const int lane = threadIdx.x & 63;
    const int node = (blockIdx.x << 2) + (threadIdx.x >> 6);
    if (node >= n) return;
    const int start = rowptr[node];
    const int len = deg[node];
    const float ad = ald[node];
    float m = -1e30f, z = 0.f, acc = 0.f;
    int k = 0;
    for (; k + 4 <= len; k += 4) {
        int s0 = csr_src[start + k + 0];
        int s1 = csr_src[start + k + 1];
        int s2 = csr_src[start + k + 2];
        int s3 = csr_src[start + k + 3];
        float a0 = als[s0], a1 = als[s1], a2 = als[s2], a3 = als[s3];
        float h0 = bf2f(h[((size_t)s0 << 6) + lane]);
        float h1 = bf2f(h[((size_t)s1 << 6) + lane]);
        float h2 = bf2f(h[((size_t)s2 << 6) + lane]);
        float h3 = bf2f(h[((size_t)s3 << 6) + lane]);
        float x0 = a0 + ad; x0 = (x0 > 0.f) ? x0 : 0.2f * x0;
        float x1 = a1 + ad; x1 = (x1 > 0.f) ? x1 : 0.2f * x1;
        float x2 = a2 + ad; x2 = (x2 > 0.f) ? x2 : 0.2f * x2;
        float x3 = a3 + ad; x3 = (x3 > 0.f) ? x3 : 0.2f * x3;
        float nm = fmaxf(fmaxf(fmaxf(x0, x1), fmaxf(x2, x3)), m);
        float c  = __expf(m - nm);
        float p0 = __expf(x0 - nm), p1 = __expf(x1 - nm);
        float p2 = __expf(x2 - nm), p3 = __expf(x3 - nm);
        m = nm;
        z = z * c + p0 + p1 + p2 + p3;
        acc = acc * c + p0 * h0 + p1 * h1 + p2 * h2 + p3 * h3;
    }
    for (; k < len; k++) {
        int s0 = csr_src[start + k];
        float x0 = als[s0] + ad; x0 = (x0 > 0.f) ? x0 : 0.2f * x0;
        float h0 = bf2f(h[((size_t)s0 << 6) + lane]);
        float nm = fmaxf(m, x0);
        float c  = __expf(m - nm);
        float p0 = __expf(x0 - nm);
        m = nm;
        z = z * c + p0;
        acc = acc * c + p0 * h0;
    }
    out[((size_t)node << 6) + lane] = acc / (z + 1e-16f) + bias[lane];
}

// ---------- mean pooling over (sorted) batch via binary search ----------
__global__ __launch_bounds__(64) void pool_kernel(const float* __restrict__ h3,
                                                  const int* __restrict__ batch,
                                                  float* __restrict__ xg) {
    const int b = blockIdx.x;
    const int j = threadIdx.x;
    int lo = 0, hi = N_NODES;
    while (lo < hi) { int mid = (lo + hi) >> 1; if (batch[mid] < b) lo = mid + 1; else hi = mid; }
    const int start = lo;
    hi = N_NODES;
    while (lo < hi) { int mid = (lo + hi) >> 1; if (batch[mid] < b + 1) lo = mid + 1; else hi = mid; }
    const int end = lo;
    float s = 0.f;
    for (int n = start; n < end; n++) s += h3[(size_t)n * CH + j];
    xg[b * CH + j] = s / fmaxf((float)(end - start), 1.f);
}

// ---------- MLP layer 2 + LayerNorm, one block per graph ----------
__global__ __launch_bounds__(256) void mlp2_ln_kernel(
    const float* __restrict__ y1, const float* __restrict__ Wm2,
    const float* __restrict__ bm2, const float* __restrict__ g2,
    const float* __restrict__ be2, float* __restrict__ out) {
    const int b = blockIdx.x;
    const int j = threadIdx.x;
    __shared__ float yr[NHID];
    yr[j] = y1[(size_t)b * NHID + j];
    __syncthreads();
    float acc = bm2[j];
#pragma unroll 8
    for (int k = 0; k < NHID; k++) acc += yr[k] * Wm2[(size_t)k * NOUT + j];
    float s = acc, s2 = acc * acc;
    for (int o = 32; o > 0; o >>= 1) {
        s += __shfl_down(s, o);
        s2 += __shfl_down(s2, o);
    }
    __shared__ float red[8];
    __shared__ float mv[2];
    int wave = j >> 6, lane = j & 63;
    if (lane == 0) { red[wave] = s; red[4 + wave] = s2; }
    __syncthreads();
    if (j == 0) {
        float ts = red[0] + red[1] + red[2] + red[3];
        float ts2 = red[4] + red[5] + red[6] + red[7];
        float mu = ts / (float)NOUT;
        float var = ts2 / (float)NOUT - mu * mu;
        mv[0] = mu;
        mv[1] = rsqrtf(var + 1e-5f);
    }
    __syncthreads();
    out[(size_t)b * NOUT + j] = (acc - mv[0]) * mv[1] * g2[j] + be2[j];
}

extern "C" void kernel_launch(void* const* d_in, const int* in_sizes, int n_in,
                              void* d_out, int out_size, void* d_ws, size_t ws_size,
                              hipStream_t stream) {
    const float* x      = (const float*)d_in[0];
    const int*   ei     = (const int*)d_in[1];
    const int*   batch  = (const int*)d_in[2];
    const float* W1     = (const float*)d_in[3];
    const float* as1    = (const float*)d_in[4];
    const float* ad1    = (const float*)d_in[5];
    const float* b1     = (const float*)d_in[6];
    const float* W2     = (const float*)d_in[7];
    const float* as2    = (const float*)d_in[8];
    const float* ad2    = (const float*)d_in[9];
    const float* b2     = (const float*)d_in[10];
    const float* W3     = (const float*)d_in[11];
    const float* as3    = (const float*)d_in[12];
    const float* ad3    = (const float*)d_in[13];
    const float* b3     = (const float*)d_in[14];
    const float* Wm1    = (const float*)d_in[15];
    const float* bm1    = (const float*)d_in[16];
    const float* Wm2    = (const float*)d_in[17];
    const float* bm2    = (const float*)d_in[18];
    const float* g2     = (const float*)d_in[19];
    const float* be2    = (const float*)d_in[20];
    float* out = (float*)d_out;

    // workspace layout
    float* bufO = (float*)d_ws;                              // N*HC fp32
    float* als  = bufO + (size_t)N_NODES * HC;               // N*HEADS
    float* ald  = als + (size_t)N_NODES * HEADS;             // N*HEADS
    float* xg   = ald + (size_t)N_NODES * HEADS;             // NB*CH
    float* y1   = xg + (size_t)NB * CH;                      // NB*NHID
    unsigned short* bufH = (unsigned short*)(y1 + (size_t)NB * NHID);  // N*HC bf16
    int* deg     = (int*)(bufH + (size_t)N_NODES * HC);      // N
    int* rowptr  = deg + N_NODES;                            // N
    int* cursor  = rowptr + N_NODES;                         // N
    int* bsum    = cursor + N_NODES;                         // <=64
    int* csr_src = bsum + 64;                                // E2
    unsigned short* wt1h = (unsigned short*)(csr_src + E2_EDGES);  // 256*32
    unsigned short* wt1l = wt1h + 256 * 32;
    unsigned short* wt2h = wt1l + 256 * 32;                        // 256*256
    unsigned short* wt2l = wt2h + 256 * 256;
    unsigned short* wt3h = wt2l + 256 * 256;                       // 64*256
    unsigned short* wt3l = wt3h + 64 * 256;

    const int BLK = 256;
    const int NSCAN = cdiv(N_NODES, 1024);

    // ===================== weight prep (split bf16, transposed) ==============
    wconv_kernel<<<cdiv(F_IN * HC, BLK), BLK, 0, stream>>>(W1, wt1h, wt1l, F_IN, HC);
    wconv_kernel<<<cdiv(HC * HC, BLK), BLK, 0, stream>>>(W2, wt2h, wt2l, HC, HC);
    wconv_kernel<<<cdiv(HC * CH, BLK), BLK, 0, stream>>>(W3, wt3h, wt3l, HC, CH);

    // ===================== CSR build (dst-sorted adjacency) ==================
    hipMemsetAsync(deg, 0, (size_t)N_NODES * sizeof(int), stream);
    hist_kernel<<<cdiv(E2_EDGES, BLK), BLK, 0, stream>>>(ei, deg);
    scan_block_kernel<<<NSCAN, 256, 0, stream>>>(deg, rowptr, bsum);
    scan_bsum_kernel<<<1, 64, 0, stream>>>(bsum, NSCAN);
    finalize_rowptr_kernel<<<cdiv(N_NODES, BLK), BLK, 0, stream>>>(rowptr, bsum, cursor);
    scatter_kernel<<<cdiv(E2_EDGES, BLK), BLK, 0, stream>>>(ei, cursor, csr_src);

    // ===================== Layer 1 (F_IN -> H*C) =====================
    mfma_lin_kernel<F_IN, HC, false, true><<<cdiv(N_NODES, 64), 256, 0, stream>>>(
        x, wt1h, wt1l, nullptr, bufH, N_NODES);
    attn_logits_kernel<HEADS, CH><<<cdiv((long long)N_NODES * HEADS, BLK), BLK, 0, stream>>>(
        bufH, as1, ad1, als, ald, N_NODES);
    gat_agg_wide_kernel<true><<<cdiv(N_NODES, 4), 256, 0, stream>>>(
        csr_src, rowptr, deg, bufH, als, ald, b1, bufO, N_NODES);

    // ===================== Layer 2 (H*C -> H*C) =====================
    mfma_lin_kernel<HC, HC, false, true><<<cdiv(N_NODES, 64), 256, 0, stream>>>(
        bufO, wt2h, wt2l, nullptr, bufH, N_NODES);
    attn_logits_kernel<HEADS, CH><<<cdiv((long long)N_NODES * HEADS, BLK), BLK, 0, stream>>>(
        bufH, as2, ad2, als, ald, N_NODES);
    gat_agg_wide_kernel<true><<<cdiv(N_NODES, 4), 256, 0, stream>>>(
        csr_src, rowptr, deg, bufH, als, ald, b2, bufO, N_NODES);

    // ===================== Layer 3 (H*C -> C, heads=1) =====================
    mfma_lin_kernel<HC, CH, false, true><<<cdiv(N_NODES, 64), 256, 0, stream>>>(
        bufO, wt3h, wt3l, nullptr, bufH, N_NODES);
    attn_logits_kernel<1, CH><<<cdiv(N_NODES, BLK), BLK, 0, stream>>>(
        bufH, as3, ad3, als, ald, N_NODES);
    gat_agg_h1_kernel<<<cdiv(N_NODES, 4), 256, 0, stream>>>(
        csr_src, rowptr, deg, bufH, als, ald, b3, bufO, N_NODES);

    // ===================== Mean pooling (batch is sorted) =====================
    pool_kernel<<<NB, 64, 0, stream>>>(bufO, batch, xg);

    // ===================== MLP head + LayerNorm =====================
    lin_kernel<CH, NHID, 16, 256, true><<<cdiv(NB, 16), 256, 0, stream>>>(
        xg, Wm1, bm1, y1, NB);
    mlp2_ln_kernel<<<NB, 256, 0, stream>>>(y1, Wm2, bm2, g2, be2, out);
}

// Round 6
// 470.681 us; speedup vs baseline: 9.5346x; 1.0292x over previous
//
#include <hip/hip_runtime.h>
#include <hip/hip_bf16.h>

#define N_NODES 50000
#define N_EDGES 500000
#define E2_EDGES 550000   // with self loops appended
#define F_IN 32
#define HEADS 4
#define CH 64
#define HC 256            // HEADS*CH
#define NB 1000
#define NHID 256
#define NOUT 256

static inline int cdiv(long long a, long long b) { return (int)((a + b - 1) / b); }

typedef __bf16 bf16x8 __attribute__((ext_vector_type(8)));
typedef unsigned short us8 __attribute__((ext_vector_type(8)));
typedef unsigned short us4 __attribute__((ext_vector_type(4)));
typedef float f32x4 __attribute__((ext_vector_type(4)));
union BU { us8 u; bf16x8 b; };

// round-to-nearest-even fp32 -> bf16 (bit pattern)
__device__ inline unsigned short f2bf(float f) {
    unsigned u = __float_as_uint(f);
    return (unsigned short)((u + 0x7fffu + ((u >> 16) & 1u)) >> 16);
}
__device__ inline float bf2f(unsigned short h) {
    return __uint_as_float(((unsigned)h) << 16);
}

// ---------- W prep: transpose + split fp32 -> (hi,lo) bf16 ----------
__global__ void wconv_kernel(const float* __restrict__ W,
                             unsigned short* __restrict__ Wt_hi,
                             unsigned short* __restrict__ Wt_lo, int K, int M) {
    int idx = blockIdx.x * blockDim.x + threadIdx.x;
    if (idx >= K * M) return;
    int k = idx / M, m = idx % M;
    float v = W[idx];
    unsigned short hi = f2bf(v);
    Wt_hi[(size_t)m * K + k] = hi;
    Wt_lo[(size_t)m * K + k] = f2bf(v - bf2f(hi));
}

// ---------- MFMA split-bf16 GEMM: C[N,M] = A[N,K] @ W[K,M] ----------
// Block covers 64 rows x MT cols (blockIdx.y = col tile). LDS rows padded to
// 40 shorts (80B): keeps ds_read_b128 16B-aligned, kills the 8-way bank
// conflict of the 64B-stride layout (8.2M conflict cycles at R5).
template<int K, int M, int MT, bool RELU, bool OBF>
__global__ __launch_bounds__(256) void mfma_lin_kernel(
    const float* __restrict__ A, const unsigned short* __restrict__ Wt_hi,
    const unsigned short* __restrict__ Wt_lo, const float* __restrict__ bias,
    void* __restrict__ Cout, int n_rows) {
    constexpr int NT = MT / 16;  // col tiles per wave
    constexpr int NCH = K / 32;  // K chunks
    constexpr int LP = 40;       // padded LDS row (shorts)
    __shared__ unsigned short As_hi[64][LP];
    __shared__ unsigned short As_lo[64][LP];
    __shared__ unsigned short Ws_hi[MT][LP];
    __shared__ unsigned short Ws_lo[MT][LP];
    const int tid = threadIdx.x;
    const int wave = tid >> 6, lane = tid & 63;
    const int quad = lane >> 4, l16 = lane & 15;
    const int row_base = blockIdx.x * 64;
    const int col0 = blockIdx.y * MT;
    const int arow = row_base + (tid >> 2);
    const int acg = (tid & 3) * 8;

    f32x4 acc[NT];
#pragma unroll
    for (int t = 0; t < NT; t++) acc[t] = (f32x4){0.f, 0.f, 0.f, 0.f};

    for (int ch = 0; ch < NCH; ch++) {
        const int k0 = ch * 32;
        // ---- stage A chunk (64 x 32) hi/lo ----
        {
            int r = tid >> 2;
            float v[8];
            if (arow < n_rows) {
                const float* ap = A + (size_t)arow * K + k0 + acg;
                float4 f0 = *(const float4*)ap;
                float4 f1 = *(const float4*)(ap + 4);
                v[0] = f0.x; v[1] = f0.y; v[2] = f0.z; v[3] = f0.w;
                v[4] = f1.x; v[5] = f1.y; v[6] = f1.z; v[7] = f1.w;
            } else {
#pragma unroll
                for (int i = 0; i < 8; i++) v[i] = 0.f;
            }
#pragma unroll
            for (int i = 0; i < 8; i++) {
                unsigned short hi = f2bf(v[i]);
                As_hi[r][acg + i] = hi;
                As_lo[r][acg + i] = f2bf(v[i] - bf2f(hi));
            }
        }
        // ---- stage W chunk (MT x 32) hi/lo ----
        for (int r = tid; r < MT; r += 256) {
            const us8* ph = (const us8*)(Wt_hi + (size_t)(col0 + r) * K + k0);
            const us8* pl = (const us8*)(Wt_lo + (size_t)(col0 + r) * K + k0);
#pragma unroll
            for (int i = 0; i < 4; i++) {
                *(us8*)&Ws_hi[r][i * 8] = ph[i];
                *(us8*)&Ws_lo[r][i * 8] = pl[i];
            }
        }
        __syncthreads();
        BU a_hi, a_lo;
        a_hi.u = *(const us8*)&As_hi[wave * 16 + l16][quad * 8];
        a_lo.u = *(const us8*)&As_lo[wave * 16 + l16][quad * 8];
#pragma unroll
        for (int t = 0; t < NT; t++) {
            BU b_hi, b_lo;
            b_hi.u = *(const us8*)&Ws_hi[t * 16 + l16][quad * 8];
            b_lo.u = *(const us8*)&Ws_lo[t * 16 + l16][quad * 8];
            acc[t] = __builtin_amdgcn_mfma_f32_16x16x32_bf16(a_hi.b, b_hi.b, acc[t], 0, 0, 0);
            acc[t] = __builtin_amdgcn_mfma_f32_16x16x32_bf16(a_hi.b, b_lo.b, acc[t], 0, 0, 0);
            acc[t] = __builtin_amdgcn_mfma_f32_16x16x32_bf16(a_lo.b, b_hi.b, acc[t], 0, 0, 0);
        }
        __syncthreads();
    }
    const int orow0 = row_base + wave * 16 + quad * 4;
#pragma unroll
    for (int t = 0; t < NT; t++) {
        float bv = bias ? bias[col0 + t * 16 + l16] : 0.f;
#pragma unroll
        for (int i = 0; i < 4; i++) {
            int r = orow0 + i;
            if (r < n_rows) {
                float v = acc[t][i] + bv;
                if (RELU) v = fmaxf(v, 0.f);
                if (OBF) ((unsigned short*)Cout)[(size_t)r * M + col0 + t * 16 + l16] = f2bf(v);
                else     ((float*)Cout)[(size_t)r * M + col0 + t * 16 + l16] = v;
            }
        }
    }
}

// ---------- generic small GEMM (MLP layer 1) ----------
template<int K, int M, int TM, int BLOCK, bool RELU>
__global__ __launch_bounds__(BLOCK) void lin_kernel(
    const float* __restrict__ A, const float* __restrict__ W,
    const float* __restrict__ bias, float* __restrict__ C, int n_rows) {
    __shared__ float As[TM][K];
    const int n0 = blockIdx.x * TM;
    const int tid = threadIdx.x;
    for (int idx = tid; idx < TM * K; idx += BLOCK) {
        int r = idx / K, c = idx % K;
        int n = n0 + r;
        As[r][c] = (n < n_rows) ? A[(size_t)n * K + c] : 0.f;
    }
    __syncthreads();
    constexpr int G = BLOCK / M;
    constexpr int RPT = TM / G;
    const int j = tid % M;
    const int g = tid / M;
    float acc[RPT];
#pragma unroll
    for (int i = 0; i < RPT; i++) acc[i] = 0.f;
    for (int k = 0; k < K; k++) {
        float wk = W[(size_t)k * M + j];
#pragma unroll
        for (int i = 0; i < RPT; i++) acc[i] += As[g * RPT + i][k] * wk;
    }
    float bv = bias ? bias[j] : 0.f;
#pragma unroll
    for (int i = 0; i < RPT; i++) {
        int n = n0 + g * RPT + i;
        if (n < n_rows) {
            float v = acc[i] + bv;
            if (RELU) v = fmaxf(v, 0.f);
            C[(size_t)n * M + j] = v;
        }
    }
}

// ---------- per-(node,head) attention logits from bf16 h ----------
template<int H_, int C_>
__global__ void attn_logits_kernel(const unsigned short* __restrict__ h,
                                   const float* __restrict__ a_src,
                                   const float* __restrict__ a_dst,
                                   float* __restrict__ als, float* __restrict__ ald,
                                   int n) {
    int t = blockIdx.x * blockDim.x + threadIdx.x;
    if (t >= n * H_) return;
    int node = t / H_, hh = t % H_;
    const us8* hp = (const us8*)(h + (size_t)node * (H_ * C_) + hh * C_);
    const float4* as = (const float4*)(a_src + hh * C_);
    const float4* ad = (const float4*)(a_dst + hh * C_);
    float ss = 0.f, sd = 0.f;
#pragma unroll
    for (int c = 0; c < C_ / 8; c++) {
        us8 hv = hp[c];
        float4 a0 = as[2 * c], a1 = as[2 * c + 1];
        float4 b0 = ad[2 * c], b1 = ad[2 * c + 1];
        float f0 = bf2f(hv[0]), f1 = bf2f(hv[1]), f2 = bf2f(hv[2]), f3 = bf2f(hv[3]);
        float f4 = bf2f(hv[4]), f5 = bf2f(hv[5]), f6 = bf2f(hv[6]), f7 = bf2f(hv[7]);
        ss += f0 * a0.x + f1 * a0.y + f2 * a0.z + f3 * a0.w
            + f4 * a1.x + f5 * a1.y + f6 * a1.z + f7 * a1.w;
        sd += f0 * b0.x + f1 * b0.y + f2 * b0.z + f3 * b0.w
            + f4 * b1.x + f5 * b1.y + f6 * b1.z + f7 * b1.w;
    }
    als[t] = ss;
    ald[t] = sd;
}

// ======================= CSR build =======================
__global__ void hist_kernel(const int* __restrict__ ei, int* __restrict__ deg) {
    int e = blockIdx.x * blockDim.x + threadIdx.x;
    if (e >= E2_EDGES) return;
    int d = (e < N_EDGES) ? ei[N_EDGES + e] : (e - N_EDGES);
    atomicAdd(deg + d, 1);
}

__global__ __launch_bounds__(256) void scan_block_kernel(const int* __restrict__ deg,
                                                         int* __restrict__ rowptr,
                                                         int* __restrict__ bsum) {
    __shared__ int sdata[256];
    const int b = blockIdx.x, t = threadIdx.x;
    const int base = b * 1024 + t * 4;
    int v[4]; int s = 0;
#pragma unroll
    for (int i = 0; i < 4; i++) {
        int idx = base + i;
        v[i] = (idx < N_NODES) ? deg[idx] : 0;
        s += v[i];
    }
    sdata[t] = s;
    __syncthreads();
    for (int o = 1; o < 256; o <<= 1) {
        int x = (t >= o) ? sdata[t - o] : 0;
        __syncthreads();
        sdata[t] += x;
        __syncthreads();
    }
    if (t == 255) bsum[b] = sdata[255];
    int run = sdata[t] - s;
#pragma unroll
    for (int i = 0; i < 4; i++) {
        int idx = base + i;
        if (idx < N_NODES) rowptr[idx] = run;
        run += v[i];
    }
}

__global__ void scan_bsum_kernel(int* __restrict__ bsum, int nb) {
    if (threadIdx.x == 0 && blockIdx.x == 0) {
        int run = 0;
        for (int i = 0; i < nb; i++) { int v = bsum[i]; bsum[i] = run; run += v; }
    }
}

__global__ void finalize_rowptr_kernel(int* __restrict__ rowptr, const int* __restrict__ bsum,
                                       int* __restrict__ cursor) {
    int i = blockIdx.x * blockDim.x + threadIdx.x;
    if (i >= N_NODES) return;
    int v = rowptr[i] + bsum[i >> 10];
    rowptr[i] = v;
    cursor[i] = v;
}

__global__ void scatter_kernel(const int* __restrict__ ei, int* __restrict__ cursor,
                               int* __restrict__ csr_src) {
    int e = blockIdx.x * blockDim.x + threadIdx.x;
    if (e >= E2_EDGES) return;
    int s, d;
    if (e < N_EDGES) { s = ei[e]; d = ei[N_EDGES + e]; }
    else             { s = d = e - N_EDGES; }
    int pos = atomicAdd(cursor + d, 1);
    csr_src[pos] = s;
}

// ======================= wide GAT agg: 1 wave/node, lane owns 4 ch (bf16 h) ==
template<bool RELU>
__global__ __launch_bounds__(256) void gat_agg_wide_kernel(
    const int* __restrict__ csr_src, const int* __restrict__ rowptr,
    const int* __restrict__ deg, const unsigned short* __restrict__ h,
    const float* __restrict__ als, const float* __restrict__ ald,
    const float* __restrict__ bias, float* __restrict__ out, int n) {
    const int lane = threadIdx.x & 63;
    const int node = (blockIdx.x << 2) + (threadIdx.x >> 6);
    if (node >= n) return;
    const int hh = lane >> 4;
    const int start = rowptr[node];
    const int len = deg[node];
    const float ad = ald[(node << 2) + hh];
    float m = -1e30f, z = 0.f;
    float4 acc = make_float4(0.f, 0.f, 0.f, 0.f);
    int k = 0;
    for (; k + 4 <= len; k += 4) {
        int s0 = csr_src[start + k + 0];
        int s1 = csr_src[start + k + 1];
        int s2 = csr_src[start + k + 2];
        int s3 = csr_src[start + k + 3];
        float a0 = als[(s0 << 2) + hh], a1 = als[(s1 << 2) + hh];
        float a2 = als[(s2 << 2) + hh], a3 = als[(s3 << 2) + hh];
        us4 h0 = *(const us4*)(h + ((size_t)s0 << 8) + (lane << 2));
        us4 h1 = *(const us4*)(h + ((size_t)s1 << 8) + (lane << 2));
        us4 h2 = *(const us4*)(h + ((size_t)s2 << 8) + (lane << 2));
        us4 h3 = *(const us4*)(h + ((size_t)s3 << 8) + (lane << 2));
        float x0 = a0 + ad; x0 = (x0 > 0.f) ? x0 : 0.2f * x0;
        float x1 = a1 + ad; x1 = (x1 > 0.f) ? x1 : 0.2f * x1;
        float x2 = a2 + ad; x2 = (x2 > 0.f) ? x2 : 0.2f * x2;
        float x3 = a3 + ad; x3 = (x3 > 0.f) ? x3 : 0.2f * x3;
        float nm = fmaxf(fmaxf(fmaxf(x0, x1), fmaxf(x2, x3)), m);
        float c  = __expf(m - nm);
        float p0 = __expf(x0 - nm), p1 = __expf(x1 - nm);
        float p2 = __expf(x2 - nm), p3 = __expf(x3 - nm);
        m = nm;
        z = z * c + p0 + p1 + p2 + p3;
        acc.x = acc.x * c + p0 * bf2f(h0[0]) + p1 * bf2f(h1[0]) + p2 * bf2f(h2[0]) + p3 * bf2f(h3[0]);
        acc.y = acc.y * c + p0 * bf2f(h0[1]) + p1 * bf2f(h1[1]) + p2 * bf2f(h2[1]) + p3 * bf2f(h3[1]);
        acc.z = acc.z * c + p0 * bf2f(h0[2]) + p1 * bf2f(h1[2]) + p2 * bf2f(h2[2]) + p3 * bf2f(h3[2]);
        acc.w = acc.w * c + p0 * bf2f(h0[3]) + p1 * bf2f(h1[3]) + p2 * bf2f(h2[3]) + p3 * bf2f(h3[3]);
    }
    for (; k < len; k++) {
        int s0 = csr_src[start + k];
        float x0 = als[(s0 << 2) + hh] + ad; x0 = (x0 > 0.f) ? x0 : 0.2f * x0;
        us4 h0 = *(const us4*)(h + ((size_t)s0 << 8) + (lane << 2));
        float nm = fmaxf(m, x0);
        float c  = __expf(m - nm);
        float p0 = __expf(x0 - nm);
        m = nm;
        z = z * c + p0;
        acc.x = acc.x * c + p0 * bf2f(h0[0]);
        acc.y = acc.y * c + p0 * bf2f(h0[1]);
        acc.z = acc.z * c + p0 * bf2f(h0[2]);
        acc.w = acc.w * c + p0 * bf2f(h0[3]);
    }
    float inv = 1.f / (z + 1e-16f);
    float4 bv = *(const float4*)(bias + (lane << 2));
    float4 v;
    v.x = acc.x * inv + bv.x;
    v.y = acc.y * inv + bv.y;
    v.z = acc.z * inv + bv.z;
    v.w = acc.w * inv + bv.w;
    if (RELU) {
        v.x = fmaxf(v.x, 0.f); v.y = fmaxf(v.y, 0.f);
        v.z = fmaxf(v.z, 0.f); v.w = fmaxf(v.w, 0.f);
    }
    *(float4*)(out + ((size_t)node << 8) + (lane << 2)) = v;
}

// ======================= layer-3 agg: H=1, C=64 (bf16 h) ======
__global__ __launch_bounds__(256) void gat_agg_h1_kernel(
    const int* __restrict__ csr_src, const int* __restrict__ rowptr,
    const int* __restrict__ deg, const unsigned short* __restrict__ h,
    const float* __restrict__ als, const float* __restrict__ ald,
    const float* __restrict__ bias, float* __restrict__ out, int n) {
    const int lane = threadIdx.x & 63;
    const int node = (blockIdx.x << 2) + (threadIdx.x >> 6);
    if (node >= n) return;
    const int start = rowptr[node];
    const int len = deg[node];
    const float ad = ald[node];
    float m = -1e30f, z = 0.f, acc = 0.f;
    int k = 0;
    for (; k + 4 <= len; k += 4) {
        int s0 = csr_src[start + k + 0];
        int s1 = csr_src[start + k + 1];
        int s2 = csr_src[start + k + 2];
        int s3 = csr_src[start + k + 3];
        float a0 = als[s0], a1 = als[s1], a2 = als[s2], a3 = als[s3];
        float h0 = bf2f(h[((size_t)s0 << 6) + lane]);
        float h1 = bf2f(h[((size_t)s1 << 6) + lane]);
        float h2 = bf2f(h[((size_t)s2 << 6) + lane]);
        float h3 = bf2f(h[((size_t)s3 << 6) + lane]);
        float x0 = a0 + ad; x0 = (x0 > 0.f) ? x0 : 0.2f * x0;
        float x1 = a1 + ad; x1 = (x1 > 0.f) ? x1 : 0.2f * x1;
        float x2 = a2 + ad; x2 = (x2 > 0.f) ? x2 : 0.2f * x2;
        float x3 = a3 + ad; x3 = (x3 > 0.f) ? x3 : 0.2f * x3;
        float nm = fmaxf(fmaxf(fmaxf(x0, x1), fmaxf(x2, x3)), m);
        float c  = __expf(m - nm);
        float p0 = __expf(x0 - nm), p1 = __expf(x1 - nm);
        float p2 = __expf(x2 - nm), p3 = __expf(x3 - nm);
        m = nm;
        z = z * c + p0 + p1 + p2 + p3;
        acc = acc * c + p0 * h0 + p1 * h1 + p2 * h2 + p3 * h3;
    }
    for (; k < len; k++) {
        int s0 = csr_src[start + k];
        float x0 = als[s0] + ad; x0 = (x0 > 0.f) ? x0 : 0.2f * x0;
        float h0 = bf2f(h[((size_t)s0 << 6) + lane]);
        float nm = fmaxf(m, x0);
        float c  = __expf(m - nm);
        float p0 = __expf(x0 - nm);
        m = nm;
        z = z * c + p0;
        acc = acc * c + p0 * h0;
    }
    out[((size_t)node << 6) + lane] = acc / (z + 1e-16f) + bias[lane];
}

// ---------- mean pooling over (sorted) batch via binary search ----------
__global__ __launch_bounds__(64) void pool_kernel(const float* __restrict__ h3,
                                                  const int* __restrict__ batch,
                                                  float* __restrict__ xg) {
    const int b = blockIdx.x;
    const int j = threadIdx.x;
    int lo = 0, hi = N_NODES;
    while (lo < hi) { int mid = (lo + hi) >> 1; if (batch[mid] < b) lo = mid + 1; else hi = mid; }
    const int start = lo;
    hi = N_NODES;
    while (lo < hi) { int mid = (lo + hi) >> 1; if (batch[mid] < b + 1) lo = mid + 1; else hi = mid; }
    const int end = lo;
    float s = 0.f;
    for (int n = start; n < end; n++) s += h3[(size_t)n * CH + j];
    xg[b * CH + j] = s / fmaxf((float)(end - start), 1.f);
}

// ---------- MLP layer 2 + LayerNorm, one block per graph ----------
__global__ __launch_bounds__(256) void mlp2_ln_kernel(
    const float* __restrict__ y1, const float* __restrict__ Wm2,
    const float* __restrict__ bm2, const float* __restrict__ g2,
    const float* __restrict__ be2, float* __restrict__ out) {
    const int b = blockIdx.x;
    const int j = threadIdx.x;
    __shared__ float yr[NHID];
    yr[j] = y1[(size_t)b * NHID + j];
    __syncthreads();
    float acc = bm2[j];
#pragma unroll 8
    for (int k = 0; k < NHID; k++) acc += yr[k] * Wm2[(size_t)k * NOUT + j];
    float s = acc, s2 = acc * acc;
    for (int o = 32; o > 0; o >>= 1) {
        s += __shfl_down(s, o);
        s2 += __shfl_down(s2, o);
    }
    __shared__ float red[8];
    __shared__ float mv[2];
    int wave = j >> 6, lane = j & 63;
    if (lane == 0) { red[wave] = s; red[4 + wave] = s2; }
    __syncthreads();
    if (j == 0) {
        float ts = red[0] + red[1] + red[2] + red[3];
        float ts2 = red[4] + red[5] + red[6] + red[7];
        float mu = ts / (float)NOUT;
        float var = ts2 / (float)NOUT - mu * mu;
        mv[0] = mu;
        mv[1] = rsqrtf(var + 1e-5f);
    }
    __syncthreads();
    out[(size_t)b * NOUT + j] = (acc - mv[0]) * mv[1] * g2[j] + be2[j];
}

extern "C" void kernel_launch(void* const* d_in, const int* in_sizes, int n_in,
                              void* d_out, int out_size, void* d_ws, size_t ws_size,
                              hipStream_t stream) {
    const float* x      = (const float*)d_in[0];
    const int*   ei     = (const int*)d_in[1];
    const int*   batch  = (const int*)d_in[2];
    const float* W1     = (const float*)d_in[3];
    const float* as1    = (const float*)d_in[4];
    const float* ad1    = (const float*)d_in[5];
    const float* b1     = (const float*)d_in[6];
    const float* W2     = (const float*)d_in[7];
    const float* as2    = (const float*)d_in[8];
    const float* ad2    = (const float*)d_in[9];
    const float* b2     = (const float*)d_in[10];
    const float* W3     = (const float*)d_in[11];
    const float* as3    = (const float*)d_in[12];
    const float* ad3    = (const float*)d_in[13];
    const float* b3     = (const float*)d_in[14];
    const float* Wm1    = (const float*)d_in[15];
    const float* bm1    = (const float*)d_in[16];
    const float* Wm2    = (const float*)d_in[17];
    const float* bm2    = (const float*)d_in[18];
    const float* g2     = (const float*)d_in[19];
    const float* be2    = (const float*)d_in[20];
    float* out = (float*)d_out;

    // workspace layout
    float* bufO = (float*)d_ws;                              // N*HC fp32
    float* als  = bufO + (size_t)N_NODES * HC;               // N*HEADS
    float* ald  = als + (size_t)N_NODES * HEADS;             // N*HEADS
    float* xg   = ald + (size_t)N_NODES * HEADS;             // NB*CH
    float* y1   = xg + (size_t)NB * CH;                      // NB*NHID
    unsigned short* bufH = (unsigned short*)(y1 + (size_t)NB * NHID);  // N*HC bf16
    int* deg     = (int*)(bufH + (size_t)N_NODES * HC);      // N
    int* rowptr  = deg + N_NODES;                            // N
    int* cursor  = rowptr + N_NODES;                         // N
    int* bsum    = cursor + N_NODES;                         // <=64
    int* csr_src = bsum + 64;                                // E2
    unsigned short* wt1h = (unsigned short*)(csr_src + E2_EDGES);  // 256*32
    unsigned short* wt1l = wt1h + 256 * 32;
    unsigned short* wt2h = wt1l + 256 * 32;                        // 256*256
    unsigned short* wt2l = wt2h + 256 * 256;
    unsigned short* wt3h = wt2l + 256 * 256;                       // 64*256
    unsigned short* wt3l = wt3h + 64 * 256;

    const int BLK = 256;
    const int NSCAN = cdiv(N_NODES, 1024);

    // ===================== weight prep (split bf16, transposed) ==============
    wconv_kernel<<<cdiv(F_IN * HC, BLK), BLK, 0, stream>>>(W1, wt1h, wt1l, F_IN, HC);
    wconv_kernel<<<cdiv(HC * HC, BLK), BLK, 0, stream>>>(W2, wt2h, wt2l, HC, HC);
    wconv_kernel<<<cdiv(HC * CH, BLK), BLK, 0, stream>>>(W3, wt3h, wt3l, HC, CH);

    // ===================== CSR build (dst-sorted adjacency) ==================
    hipMemsetAsync(deg, 0, (size_t)N_NODES * sizeof(int), stream);
    hist_kernel<<<cdiv(E2_EDGES, BLK), BLK, 0, stream>>>(ei, deg);
    scan_block_kernel<<<NSCAN, 256, 0, stream>>>(deg, rowptr, bsum);
    scan_bsum_kernel<<<1, 64, 0, stream>>>(bsum, NSCAN);
    finalize_rowptr_kernel<<<cdiv(N_NODES, BLK), BLK, 0, stream>>>(rowptr, bsum, cursor);
    scatter_kernel<<<cdiv(E2_EDGES, BLK), BLK, 0, stream>>>(ei, cursor, csr_src);

    // ===================== Layer 1 (F_IN -> H*C) =====================
    mfma_lin_kernel<F_IN, HC, 128, false, true>
        <<<dim3(cdiv(N_NODES, 64), 2), 256, 0, stream>>>(
        x, wt1h, wt1l, nullptr, bufH, N_NODES);
    attn_logits_kernel<HEADS, CH><<<cdiv((long long)N_NODES * HEADS, BLK), BLK, 0, stream>>>(
        bufH, as1, ad1, als, ald, N_NODES);
    gat_agg_wide_kernel<true><<<cdiv(N_NODES, 4), 256, 0, stream>>>(
        csr_src, rowptr, deg, bufH, als, ald, b1, bufO, N_NODES);

    // ===================== Layer 2 (H*C -> H*C) =====================
    mfma_lin_kernel<HC, HC, 128, false, true>
        <<<dim3(cdiv(N_NODES, 64), 2), 256, 0, stream>>>(
        bufO, wt2h, wt2l, nullptr, bufH, N_NODES);
    attn_logits_kernel<HEADS, CH><<<cdiv((long long)N_NODES * HEADS, BLK), BLK, 0, stream>>>(
        bufH, as2, ad2, als, ald, N_NODES);
    gat_agg_wide_kernel<true><<<cdiv(N_NODES, 4), 256, 0, stream>>>(
        csr_src, rowptr, deg, bufH, als, ald, b2, bufO, N_NODES);

    // ===================== Layer 3 (H*C -> C, heads=1) =====================
    mfma_lin_kernel<HC, CH, 64, false, true>
        <<<dim3(cdiv(N_NODES, 64), 1), 256, 0, stream>>>(
        bufO, wt3h, wt3l, nullptr, bufH, N_NODES);
    attn_logits_kernel<1, CH><<<cdiv(N_NODES, BLK), BLK, 0, stream>>>(
        bufH, as3, ad3, als, ald, N_NODES);
    gat_agg_h1_kernel<<<cdiv(N_NODES, 4), 256, 0, stream>>>(
        csr_src, rowptr, deg, bufH, als, ald, b3, bufO, N_NODES);

    // ===================== Mean pooling (batch is sorted) =====================
    pool_kernel<<<NB, 64, 0, stream>>>(bufO, batch, xg);

    // ===================== MLP head + LayerNorm =====================
    lin_kernel<CH, NHID, 16, 256, true><<<cdiv(NB, 16), 256, 0, stream>>>(
        xg, Wm1, bm1, y1, NB);
    mlp2_ln_kernel<<<NB, 256, 0, stream>>>(y1, Wm2, bm2, g2, be2, out);
}